// Round 14
// baseline (352.393 us; speedup 1.0000x reference)
//
#include <hip/hip_runtime.h>
#include <hip/hip_bf16.h>
#include <math.h>

// ---------------------------------------------------------------------------
// MoE gate, approximate-then-refine (round 14):
//  1. approx GEMM: logits_a = xh·wh/64 (single fp16 product; score noise
//     sigma <= 8.5e-5). r11 structure minus lo-limb -> 3 waves/SIMD.
//  2. screen: route on approx scores; flag token if ANY decision gap
//     (9 selection gaps, group-4/5 gap) < MARGIN (23 sigma); write approx
//     outputs; compact flagged tokens.
//  3. refine: flagged tokens only, full r5-validated numerics
//     (fp16 hi/lo 3-product, KS=8, fp64 combine) -> overwrite outputs.
// Unflagged indices provably exact; weights error ~4e-4 << 5.1e-3.
// ---------------------------------------------------------------------------

#define MARGIN  2.0e-3f
#define GMARGIN 4.0e-3f

typedef _Float16 f16x8 __attribute__((ext_vector_type(8)));
typedef float    f32x4 __attribute__((ext_vector_type(4)));

__device__ __forceinline__ void glds16(const void* g, void* l) {
  __builtin_amdgcn_global_load_lds(
      (const __attribute__((address_space(1))) void*)g,
      (__attribute__((address_space(3))) void*)l, 16, 0, 0);
}
__device__ __forceinline__ unsigned short f2h(float f) {
  _Float16 h = (_Float16)f;
  return __builtin_bit_cast(unsigned short, h);
}
__device__ __forceinline__ float h2f(unsigned short b) {
  return (float)__builtin_bit_cast(_Float16, b);
}
__device__ __forceinline__ int swz(int gi, int row) {
  return gi ^ (row & 3) ^ ((row >> 2) & 3);
}

// ---------------------------------------------------------------------------
// W -> Whi/Wlo fp16 pre-swizzled tiles (r11 layout, validated):
// tile (bn,s) = 128 rows x 32 f16; addr = tile*4096 + r*32 + swz(gi,r)*8+(k&7)
// Also zeroes the flagged-token counter.
// ---------------------------------------------------------------------------
__global__ __launch_bounds__(256) void convert_w(
    const float* __restrict__ W,
    unsigned short* __restrict__ Whi, unsigned short* __restrict__ Wlo,
    int* __restrict__ cnt)
{
  const int e = blockIdx.x;
  const int t = threadIdx.x;
  if (t >= 224) { if (e == 0 && t == 224) *cnt = 0; return; }
  const int r = e & 127, bn = e >> 7;
  const float* src = W + (size_t)e * 7168 + t * 32;
  const size_t tbase = (size_t)(bn * 224 + t) * 4096 + (size_t)r * 32;
  #pragma unroll
  for (int g = 0; g < 4; ++g) {
    unsigned int hw[4], lw[4];
    #pragma unroll
    for (int p = 0; p < 4; ++p) {
      float f0 = src[g * 8 + 2 * p] * 64.0f;
      float f1 = src[g * 8 + 2 * p + 1] * 64.0f;
      unsigned short h0 = f2h(f0), h1 = f2h(f1);
      unsigned short l0 = f2h((f0 - h2f(h0)) * 2048.0f);
      unsigned short l1 = f2h((f1 - h2f(h1)) * 2048.0f);
      hw[p] = (unsigned)h0 | ((unsigned)h1 << 16);
      lw[p] = (unsigned)l0 | ((unsigned)l1 << 16);
    }
    const size_t base = tbase + (size_t)(swz(g, r) * 8);
    *(uint4*)(Whi + base) = make_uint4(hw[0], hw[1], hw[2], hw[3]);
    *(uint4*)(Wlo + base) = make_uint4(lw[0], lw[1], lw[2], lw[3]);
  }
}

// ---------------------------------------------------------------------------
// APPROX GEMM: single product xh·wh. r11 geometry (BM=128,BN=128,BK=32,
// KS, 4 waves, wave 64x64) minus lo-limb: LDS 2x16KB, acc 64 regs ->
// 3 waves/SIMD. Writes Spart[ks][t][e] = acc/64.
// ---------------------------------------------------------------------------
__global__ __launch_bounds__(256, 3) void gate_gemm_approx(
    const float* __restrict__ X,
    const unsigned short* __restrict__ Whi,
    float* __restrict__ Spart, int D, int TILES, int KS)
{
  __shared__ char lds[32768];   // buf b at b*16384: Ahi +0 (8KB), Bh +8192

  const int bid = blockIdx.x;
  const int ks = bid % KS;
  const int bn = (bid / KS) & 1;
  const int bm = bid / (2 * KS);
  const int tid = threadIdx.x, lane = tid & 63, wid = tid >> 6;
  const int wm = wid >> 1, wn = wid & 1;
  const int TM = bm * 128;
  const int k0base = ks * TILES * 32;

  const int srow = tid >> 1, skq = tid & 1;
  const float* xsrc = X + (size_t)(TM + srow) * D + k0base + skq * 16;
  const int aw0 = srow * 64 + swz(skq * 2 + 0, srow) * 16;
  const int aw1 = srow * 64 + swz(skq * 2 + 1, srow) * 16;

  const unsigned short* wh_tile = Whi + (size_t)(bn * 224 + ks * TILES) * 4096;

  f32x4 acc[4][4];
  #pragma unroll
  for (int m = 0; m < 4; ++m)
    #pragma unroll
    for (int n = 0; n < 4; ++n) acc[m][n] = (f32x4)0.0f;

  int aro[4], bro[4];
  const int gi = lane >> 4;
  #pragma unroll
  for (int m = 0; m < 4; ++m) {
    const int row = wm * 64 + m * 16 + (lane & 15);
    aro[m] = row * 64 + swz(gi, row) * 16;
  }
  #pragma unroll
  for (int n = 0; n < 4; ++n) {
    const int row = wn * 64 + n * 16 + (lane & 15);
    bro[n] = row * 64 + swz(gi, row) * 16;
  }

  float4 pa[4], pb[4];
  {
    #pragma unroll
    for (int i = 0; i < 2; ++i) {
      const int c = wid * 2 + i;
      glds16(wh_tile + c * 512 + lane * 8, lds + 8192 + c * 1024);
    }
    __builtin_amdgcn_sched_barrier(0);
    float4 a[4];
    #pragma unroll
    for (int i = 0; i < 4; ++i) a[i] = *(const float4*)(xsrc + i * 4);
    unsigned int hw[8];
    #pragma unroll
    for (int q = 0; q < 8; ++q) {
      float f0 = ((const float*)a)[2 * q], f1 = ((const float*)a)[2 * q + 1];
      hw[q] = (unsigned)f2h(f0) | ((unsigned)f2h(f1) << 16);
    }
    *(uint4*)(lds + aw0) = make_uint4(hw[0], hw[1], hw[2], hw[3]);
    *(uint4*)(lds + aw1) = make_uint4(hw[4], hw[5], hw[6], hw[7]);
    const int s1 = (TILES > 1) ? 1 : 0;
    #pragma unroll
    for (int i = 0; i < 4; ++i)
      pa[i] = *(const float4*)(xsrc + (size_t)s1 * 32 + i * 4);
    __builtin_amdgcn_sched_barrier(0);
  }
  asm volatile("s_waitcnt vmcnt(4) lgkmcnt(0)" ::: "memory");
  __builtin_amdgcn_sched_barrier(0);
  __builtin_amdgcn_s_barrier();

  int cur = 0;
  for (int s = 0; s < TILES; ++s) {
    char* base_c = lds + cur * 16384;
    char* base_n = lds + (cur ^ 1) * 16384;
    const bool stage_next = (s + 1 < TILES);

    if (stage_next) {
      const unsigned short* wh = wh_tile + (size_t)(s + 1) * 4096;
      #pragma unroll
      for (int i = 0; i < 2; ++i) {
        const int c = wid * 2 + i;
        glds16(wh + c * 512 + lane * 8, base_n + 8192 + c * 1024);
      }
    }
    __builtin_amdgcn_sched_barrier(0);
    {
      int sn = s + 2; if (sn > TILES - 1) sn = TILES - 1;
      #pragma unroll
      for (int i = 0; i < 4; ++i)
        pb[i] = *(const float4*)(xsrc + (size_t)sn * 32 + i * 4);
    }
    __builtin_amdgcn_sched_barrier(0);
    {
      f16x8 ah[4], bh[4];
      #pragma unroll
      for (int m = 0; m < 4; ++m) ah[m] = *(const f16x8*)(base_c + aro[m]);
      #pragma unroll
      for (int n = 0; n < 4; ++n) bh[n] = *(const f16x8*)(base_c + 8192 + bro[n]);
      __builtin_amdgcn_s_setprio(1);
      #pragma unroll
      for (int m = 0; m < 4; ++m)
        #pragma unroll
        for (int n = 0; n < 4; ++n)
          acc[m][n] = __builtin_amdgcn_mfma_f32_16x16x32_f16(ah[m], bh[n], acc[m][n], 0, 0, 0);
      __builtin_amdgcn_s_setprio(0);
    }
    if (stage_next) {
      unsigned int hw[8];
      #pragma unroll
      for (int q = 0; q < 8; ++q) {
        float f0 = ((const float*)pa)[2 * q], f1 = ((const float*)pa)[2 * q + 1];
        hw[q] = (unsigned)f2h(f0) | ((unsigned)f2h(f1) << 16);
      }
      *(uint4*)(base_n + aw0) = make_uint4(hw[0], hw[1], hw[2], hw[3]);
      *(uint4*)(base_n + aw1) = make_uint4(hw[4], hw[5], hw[6], hw[7]);
    }
    #pragma unroll
    for (int i = 0; i < 4; ++i) pa[i] = pb[i];

    asm volatile("s_waitcnt vmcnt(4) lgkmcnt(0)" ::: "memory");
    __builtin_amdgcn_sched_barrier(0);
    __builtin_amdgcn_s_barrier();
    cur ^= 1;
  }

  float* Sp = Spart + (size_t)ks * 8192 * 256;
  #pragma unroll
  for (int m = 0; m < 4; ++m)
    #pragma unroll
    for (int n = 0; n < 4; ++n)
      #pragma unroll
      for (int r = 0; r < 4; ++r) {
        const int t = TM + wm * 64 + m * 16 + (lane >> 4) * 4 + r;
        const int e = bn * 128 + wn * 64 + n * 16 + (lane & 15);
        Sp[(size_t)t * 256 + e] = acc[m][n][r] * (1.0f / 64.0f);
      }
}

// ---------------------------------------------------------------------------
// SCREEN: route on approx scores; write outputs for all tokens; flag and
// compact tokens whose decision gaps are within MARGIN of flipping.
// ---------------------------------------------------------------------------
__global__ __launch_bounds__(256) void gate_screen(
    const float* __restrict__ Spart, int KS,
    const float* __restrict__ bias,
    float* __restrict__ outw, float* __restrict__ outi, int T,
    int* __restrict__ cnt, int* __restrict__ list)
{
  const int lane = threadIdx.x & 63;
  const int wave = threadIdx.x >> 6;
  const int t = blockIdx.x * 4 + wave;
  if (t >= T) return;

  double l[4] = {0.0, 0.0, 0.0, 0.0};
  for (int ks = 0; ks < KS; ++ks) {
    float4 p = *(const float4*)(Spart + (size_t)ks * T * 256
                                + (size_t)t * 256 + lane * 4);
    l[0] += (double)p.x; l[1] += (double)p.y;
    l[2] += (double)p.z; l[3] += (double)p.w;
  }

  float4 bi = *(const float4*)(bias + lane * 4);
  float orig[4], s[4];
  #pragma unroll
  for (int u = 0; u < 4; ++u)
    orig[u] = 1.0f / (1.0f + expf(-(float)l[u]));
  s[0] = orig[0] + bi.x; s[1] = orig[1] + bi.y;
  s[2] = orig[2] + bi.z; s[3] = orig[3] + bi.w;

  // per-lane top-2, group merge (validated)
  float m1 = -INFINITY, m2 = -INFINITY;
  #pragma unroll
  for (int u = 0; u < 4; ++u) {
    float v = s[u];
    if (v > m1) { m2 = m1; m1 = v; }
    else if (v > m2) { m2 = v; }
  }
  #pragma unroll
  for (int off = 1; off < 8; off <<= 1) {
    float o1 = __shfl_xor(m1, off, 64);
    float o2 = __shfl_xor(m2, off, 64);
    if (o1 > m1) { m2 = fmaxf(m1, o2); m1 = o1; }
    else         { m2 = fmaxf(m2, o1); }
  }
  const float gscore = m1 + m2;

  const int g = lane >> 3;
  int rank = 0;
  float g4 = -INFINITY, g5 = -INFINITY;
  #pragma unroll
  for (int j = 0; j < 8; ++j) {
    float gs = __shfl(gscore, j * 8, 64);
    rank += (gs > gscore || (gs == gscore && j < g)) ? 1 : 0;
    // rank of group j among all groups
    int rj = 0;
    #pragma unroll
    for (int jj = 0; jj < 8; ++jj) {
      float gjj = __shfl(gscore, jj * 8, 64);
      rj += (gjj > gs || (gjj == gs && jj < j)) ? 1 : 0;
    }
    if (rj == 3) g4 = gs;
    if (rj == 4) g5 = gs;
  }
  if (rank >= 4) { s[0] = s[1] = s[2] = s[3] = -INFINITY; }

  // top-8 selection + one extra iteration for the 9th; track min gap
  float wsum = 0.0f, sel_w = 0.0f;
  int sel_i = 0;
  float prev_v = 0.0f, gapmin = INFINITY;
  for (int it = 0; it < 9; ++it) {
    float bv = s[0]; int bu = 0;
    #pragma unroll
    for (int u = 1; u < 4; ++u)
      if (s[u] > bv) { bv = s[u]; bu = u; }
    float v = bv;
    int ix = lane * 4 + bu;
    float og = orig[bu];
    #pragma unroll
    for (int off = 1; off < 64; off <<= 1) {
      float ov  = __shfl_xor(v,  off, 64);
      int   oix = __shfl_xor(ix, off, 64);
      float oog = __shfl_xor(og, off, 64);
      if (ov > v || (ov == v && oix < ix)) { v = ov; ix = oix; og = oog; }
    }
    if (it > 0) gapmin = fminf(gapmin, prev_v - v);
    prev_v = v;
    if (it < 8) {
      if (lane == it) { sel_w = og; sel_i = ix; }
      wsum += og;
      if ((ix >> 2) == lane) s[ix & 3] = -INFINITY;
    }
  }

  if (lane < 8) {
    outw[(size_t)t * 8 + lane] = sel_w / wsum * 2.5f;
    outi[(size_t)t * 8 + lane] = (float)sel_i;
  }

  const bool flag = (g4 - g5 < GMARGIN) || (gapmin < MARGIN);
  if (flag && lane == 0) {
    int pos = atomicAdd(cnt, 1);
    list[pos] = t;
  }
}

// ---------------------------------------------------------------------------
// REFINE GEMM: flagged tokens only, full 3-product fp16 split (r5-r12
// numerics). BM=32 (token slots), BN=256, BK=32, KS. Wave tile 32x64.
// Writes Rpart[ks][slot][e] = (acc1 + acc2/2048)/64.
// ---------------------------------------------------------------------------
__global__ __launch_bounds__(256, 2) void gate_refine_gemm(
    const float* __restrict__ X,
    const unsigned short* __restrict__ Whi,
    const unsigned short* __restrict__ Wlo,
    float* __restrict__ Rpart, int D, int TILES, int KS,
    const int* __restrict__ cnt, const int* __restrict__ list)
{
  const int count = *cnt;
  const int bid = blockIdx.x;
  const int ks = bid % KS;
  const int bm = bid / KS;
  if (bm * 32 >= count) return;

  __shared__ char lds[73728];
  // buf b at b*36864: Ahi +0 (2KB), Alo +2048, Bh +4096 (16KB), Bl +20480

  const int tid = threadIdx.x, lane = tid & 63, wid = tid >> 6;
  const int k0base = ks * TILES * 32;

  // A staging: 8 threads per row, 4 fp32 each (half granule)
  const int srow = tid >> 3, sub = tid & 7;
  const int sgi = sub >> 1, shalf = sub & 1;
  int slot = bm * 32 + srow;
  int sl = slot < count ? slot : count - 1;
  const int tok = list[sl];
  const float* xsrc = X + (size_t)tok * D + k0base + sub * 4;
  const int aw = srow * 64 + swz(sgi, srow) * 16 + shalf * 8;

  const unsigned short* wh_t0 = Whi + (size_t)(ks * TILES) * 4096;
  const unsigned short* wh_t1 = Whi + (size_t)(224 + ks * TILES) * 4096;
  const unsigned short* wl_t0 = Wlo + (size_t)(ks * TILES) * 4096;
  const unsigned short* wl_t1 = Wlo + (size_t)(224 + ks * TILES) * 4096;

  f32x4 acc1[2][4], acc2[2][4];
  #pragma unroll
  for (int m = 0; m < 2; ++m)
    #pragma unroll
    for (int n = 0; n < 4; ++n) { acc1[m][n] = (f32x4)0.0f; acc2[m][n] = (f32x4)0.0f; }

  int aro[2], bro[4];
  const int gi = lane >> 4;
  #pragma unroll
  for (int m = 0; m < 2; ++m) {
    const int row = m * 16 + (lane & 15);
    aro[m] = row * 64 + swz(gi, row) * 16;
  }
  #pragma unroll
  for (int n = 0; n < 4; ++n) {
    const int row = wid * 64 + n * 16 + (lane & 15);
    bro[n] = row * 64 + swz(gi, row) * 16;
  }

  float4 pa, pb;
  // prologue: stage tile 0; prefetch A(1)
  {
    #pragma unroll
    for (int i = 0; i < 4; ++i) {
      const int c = wid * 4 + i;    // 16 chunks of 16 rows
      const unsigned short* sh = (c < 8) ? (wh_t0 + (c & 7) * 512)
                                         : (wh_t1 + (c & 7) * 512);
      const unsigned short* slo = (c < 8) ? (wl_t0 + (c & 7) * 512)
                                          : (wl_t1 + (c & 7) * 512);
      glds16(sh + lane * 8, lds + 4096 + c * 1024);
      glds16(slo + lane * 8, lds + 20480 + c * 1024);
    }
    __builtin_amdgcn_sched_barrier(0);
    float4 a = *(const float4*)(xsrc);
    unsigned int hw[2], lw[2];
    const float ff[4] = {a.x, a.y, a.z, a.w};
    #pragma unroll
    for (int q = 0; q < 2; ++q) {
      float f0 = ff[2 * q], f1 = ff[2 * q + 1];
      unsigned short h0 = f2h(f0), h1 = f2h(f1);
      unsigned short l0 = f2h((f0 - h2f(h0)) * 2048.0f);
      unsigned short l1 = f2h((f1 - h2f(h1)) * 2048.0f);
      hw[q] = (unsigned)h0 | ((unsigned)h1 << 16);
      lw[q] = (unsigned)l0 | ((unsigned)l1 << 16);
    }
    *(uint2*)(lds + aw)        = make_uint2(hw[0], hw[1]);
    *(uint2*)(lds + 2048 + aw) = make_uint2(lw[0], lw[1]);
    const int s1 = (TILES > 1) ? 1 : 0;
    pa = *(const float4*)(xsrc + (size_t)s1 * 32);
    __builtin_amdgcn_sched_barrier(0);
  }
  asm volatile("s_waitcnt vmcnt(1) lgkmcnt(0)" ::: "memory");
  __builtin_amdgcn_sched_barrier(0);
  __builtin_amdgcn_s_barrier();

  int cur = 0;
  for (int s = 0; s < TILES; ++s) {
    char* base_c = lds + cur * 36864;
    char* base_n = lds + (cur ^ 1) * 36864;
    const bool stage_next = (s + 1 < TILES);

    if (stage_next) {
      #pragma unroll
      for (int i = 0; i < 4; ++i) {
        const int c = wid * 4 + i;
        const unsigned short* sh = ((c < 8) ? wh_t0 : wh_t1)
                                   + (size_t)(s + 1) * 4096 + (c & 7) * 512;
        const unsigned short* slo = ((c < 8) ? wl_t0 : wl_t1)
                                    + (size_t)(s + 1) * 4096 + (c & 7) * 512;
        glds16(sh + lane * 8, base_n + 4096 + c * 1024);
        glds16(slo + lane * 8, base_n + 20480 + c * 1024);
      }
    }
    __builtin_amdgcn_sched_barrier(0);
    {
      int sn = s + 2; if (sn > TILES - 1) sn = TILES - 1;
      pb = *(const float4*)(xsrc + (size_t)sn * 32);
    }
    __builtin_amdgcn_sched_barrier(0);
    {
      f16x8 ah[2], al[2], bh[4], bl[4];
      #pragma unroll
      for (int m = 0; m < 2; ++m) {
        ah[m] = *(const f16x8*)(base_c + aro[m]);
        al[m] = *(const f16x8*)(base_c + 2048 + aro[m]);
      }
      #pragma unroll
      for (int n = 0; n < 4; ++n) {
        bh[n] = *(const f16x8*)(base_c + 4096 + bro[n]);
        bl[n] = *(const f16x8*)(base_c + 20480 + bro[n]);
      }
      __builtin_amdgcn_s_setprio(1);
      #pragma unroll
      for (int m = 0; m < 2; ++m)
        #pragma unroll
        for (int n = 0; n < 4; ++n) {
          acc1[m][n] = __builtin_amdgcn_mfma_f32_16x16x32_f16(ah[m], bh[n], acc1[m][n], 0, 0, 0);
          acc2[m][n] = __builtin_amdgcn_mfma_f32_16x16x32_f16(ah[m], bl[n], acc2[m][n], 0, 0, 0);
          acc2[m][n] = __builtin_amdgcn_mfma_f32_16x16x32_f16(al[m], bh[n], acc2[m][n], 0, 0, 0);
        }
      __builtin_amdgcn_s_setprio(0);
    }
    if (stage_next) {
      unsigned int hw[2], lw[2];
      const float ff[4] = {pa.x, pa.y, pa.z, pa.w};
      #pragma unroll
      for (int q = 0; q < 2; ++q) {
        float f0 = ff[2 * q], f1 = ff[2 * q + 1];
        unsigned short h0 = f2h(f0), h1 = f2h(f1);
        unsigned short l0 = f2h((f0 - h2f(h0)) * 2048.0f);
        unsigned short l1 = f2h((f1 - h2f(h1)) * 2048.0f);
        hw[q] = (unsigned)h0 | ((unsigned)h1 << 16);
        lw[q] = (unsigned)l0 | ((unsigned)l1 << 16);
      }
      *(uint2*)(base_n + aw)        = make_uint2(hw[0], hw[1]);
      *(uint2*)(base_n + 2048 + aw) = make_uint2(lw[0], lw[1]);
    }
    pa = pb;

    asm volatile("s_waitcnt vmcnt(1) lgkmcnt(0)" ::: "memory");
    __builtin_amdgcn_sched_barrier(0);
    __builtin_amdgcn_s_barrier();
    cur ^= 1;
  }

  float* Rp = Rpart + (size_t)ks * 8192 * 256;
  #pragma unroll
  for (int m = 0; m < 2; ++m)
    #pragma unroll
    for (int n = 0; n < 4; ++n)
      #pragma unroll
      for (int r = 0; r < 4; ++r) {
        const int so = bm * 32 + m * 16 + (lane >> 4) * 4 + r;
        const int e = wid * 64 + n * 16 + (lane & 15);
        Rp[(size_t)so * 256 + e] =
            (acc1[m][n][r] + acc2[m][n][r] * (1.0f / 2048.0f)) * (1.0f / 64.0f);
      }
}

// ---------------------------------------------------------------------------
// REFINE ROUTE: one wave per flagged slot; exact logits = fp64 sum of KS
// partials; full routing (validated); overwrite outputs for that token.
// ---------------------------------------------------------------------------
__global__ __launch_bounds__(256) void gate_refine_route(
    const float* __restrict__ Rpart, int KS,
    const float* __restrict__ bias,
    float* __restrict__ outw, float* __restrict__ outi, int T,
    const int* __restrict__ cnt, const int* __restrict__ list)
{
  const int lane = threadIdx.x & 63;
  const int wave = threadIdx.x >> 6;
  const int slot = blockIdx.x * 4 + wave;
  if (slot >= *cnt) return;
  const int t = list[slot];

  double l[4] = {0.0, 0.0, 0.0, 0.0};
  for (int ks = 0; ks < KS; ++ks) {
    float4 p = *(const float4*)(Rpart + (size_t)ks * T * 256
                                + (size_t)slot * 256 + lane * 4);
    l[0] += (double)p.x; l[1] += (double)p.y;
    l[2] += (double)p.z; l[3] += (double)p.w;
  }

  float4 bi = *(const float4*)(bias + lane * 4);
  float orig[4], s[4];
  #pragma unroll
  for (int u = 0; u < 4; ++u)
    orig[u] = 1.0f / (1.0f + expf(-(float)l[u]));
  s[0] = orig[0] + bi.x; s[1] = orig[1] + bi.y;
  s[2] = orig[2] + bi.z; s[3] = orig[3] + bi.w;

  float m1 = -INFINITY, m2 = -INFINITY;
  #pragma unroll
  for (int u = 0; u < 4; ++u) {
    float v = s[u];
    if (v > m1) { m2 = m1; m1 = v; }
    else if (v > m2) { m2 = v; }
  }
  #pragma unroll
  for (int off = 1; off < 8; off <<= 1) {
    float o1 = __shfl_xor(m1, off, 64);
    float o2 = __shfl_xor(m2, off, 64);
    if (o1 > m1) { m2 = fmaxf(m1, o2); m1 = o1; }
    else         { m2 = fmaxf(m2, o1); }
  }
  const float gscore = m1 + m2;

  const int g = lane >> 3;
  int rank = 0;
  #pragma unroll
  for (int j = 0; j < 8; ++j) {
    float gs = __shfl(gscore, j * 8, 64);
    rank += (gs > gscore || (gs == gscore && j < g)) ? 1 : 0;
  }
  if (rank >= 4) { s[0] = s[1] = s[2] = s[3] = -INFINITY; }

  float wsum = 0.0f, sel_w = 0.0f;
  int sel_i = 0;
  #pragma unroll
  for (int it = 0; it < 8; ++it) {
    float bv = s[0]; int bu = 0;
    #pragma unroll
    for (int u = 1; u < 4; ++u)
      if (s[u] > bv) { bv = s[u]; bu = u; }
    float v = bv;
    int ix = lane * 4 + bu;
    float og = orig[bu];
    #pragma unroll
    for (int off = 1; off < 64; off <<= 1) {
      float ov  = __shfl_xor(v,  off, 64);
      int   oix = __shfl_xor(ix, off, 64);
      float oog = __shfl_xor(og, off, 64);
      if (ov > v || (ov == v && oix < ix)) { v = ov; ix = oix; og = oog; }
    }
    if (lane == it) { sel_w = og; sel_i = ix; }
    wsum += og;
    if ((ix >> 2) == lane) s[ix & 3] = -INFINITY;
  }

  if (lane < 8) {
    outw[(size_t)t * 8 + lane] = sel_w / wsum * 2.5f;
    outi[(size_t)t * 8 + lane] = (float)sel_i;
  }
}

extern "C" void kernel_launch(void* const* d_in, const int* in_sizes, int n_in,
                              void* d_out, int out_size, void* d_ws, size_t ws_size,
                              hipStream_t stream) {
  const float* x = (const float*)d_in[0];
  const float* w = (const float*)d_in[1];
  const float* b = (const float*)d_in[2];
  const int E = in_sizes[2];                  // 256
  const int D = in_sizes[1] / E;              // 7168
  const int T = in_sizes[0] / D;              // 8192

  // adaptive K-split: {8,4} by workspace
  const size_t per_part = (size_t)T * E * 4;
  int KS = 4;
  if (ws_size >= (8u << 20) + 8 * per_part + (1u << 20)) KS = 8;
  const int TILES = D / (32 * KS);

  unsigned short* Whi = (unsigned short*)d_ws;                       // 4 MB
  unsigned short* Wlo = (unsigned short*)((char*)d_ws + (4u << 20)); // 4 MB
  float* Spart = (float*)((char*)d_ws + (8u << 20));                 // KS x 8 MB
  float* Rpart = Spart;   // overlay: Spart consumed by screen before refine
  char*  tail  = (char*)d_ws + (8u << 20) + (size_t)KS * per_part;
  int*   cnt   = (int*)tail;
  int*   list  = (int*)(tail + 1024);

  float* outw = (float*)d_out;
  float* outi = outw + (size_t)T * 8;

  convert_w<<<E, 256, 0, stream>>>(w, Whi, Wlo, cnt);
  gate_gemm_approx<<<2 * KS * (T / 128), 256, 0, stream>>>(
      x, Whi, Spart, D, TILES, KS);
  gate_screen<<<(T + 3) / 4, 256, 0, stream>>>(
      Spart, KS, b, outw, outi, T, cnt, list);
  gate_refine_gemm<<<(T / 32) * KS, 256, 0, stream>>>(
      x, Whi, Wlo, Rpart, D, TILES, KS, cnt, list);
  gate_refine_route<<<(T + 3) / 4, 256, 0, stream>>>(
      Rpart, KS, b, outw, outi, T, cnt, list);
}

// Round 15
// 159.424 us; speedup vs baseline: 2.2104x; 2.2104x over previous
//
#include <hip/hip_runtime.h>
#include <hip/hip_bf16.h>
#include <math.h>

// ---------------------------------------------------------------------------
// MoE gate via fp16 hi/lo split MFMA, 3 products (validated round 5):
//   x = xh + xl/2048,  W*64 = wh + wl/2048
//   logit = ( xh·wh + (xh·wl + xl·wh)/2048 ) / 64
// Round 15 = round 11 (best: 147.4us) with the MFMA switched from
// 16x16x32 to 32x32x16 f16: same FLOP, ~20% faster pipe (m119: 2495 vs
// 2075 TF), half the MFMA instructions, identical LDS layout/staging.
// Wave tile 64x64 = 2x2 frags of 32x32. A-frag read: row=lane&31,
// k-granule = ks2*2 + (lane>>5) -> same swizzled 16B read as before.
// C/D (HW-verified m74/m101): col=lane&31, row=(reg&3)+8*(reg>>2)+4*(lane>>5).
// Numerics / staging / routing byte-identical to round 11 (passed).
// ---------------------------------------------------------------------------

typedef _Float16 f16x8  __attribute__((ext_vector_type(8)));
typedef float    f32x16 __attribute__((ext_vector_type(16)));

__device__ __forceinline__ void glds16(const void* g, void* l) {
  __builtin_amdgcn_global_load_lds(
      (const __attribute__((address_space(1))) void*)g,
      (__attribute__((address_space(3))) void*)l, 16, 0, 0);
}

__device__ __forceinline__ unsigned short f2h(float f) {
  _Float16 h = (_Float16)f;                       // v_cvt_f16_f32, RTN
  return __builtin_bit_cast(unsigned short, h);
}
__device__ __forceinline__ float h2f(unsigned short b) {
  return (float)__builtin_bit_cast(_Float16, b);
}

// swizzle: 64B rows, 4 granules of 16B; bijective in gi per row.
__device__ __forceinline__ int swz(int gi, int row) {
  return gi ^ (row & 3) ^ ((row >> 2) & 3);
}

// ---------------------------------------------------------------------------
// W [256][7168] fp32 -> Whi/Wlo fp16, tiled pre-swizzled layout (BK=32):
// tile (bn in 0..1, s in 0..223) = 128 rows x 32 f16 = 4096 ushorts (8KB).
// element (r,k): gi=(k&31)>>3, addr = tile*4096 + r*32 + swz(gi,r)*8 + (k&7)
// Whi = fp16(64*W); Wlo = fp16((64*W - Whi) * 2048).
// ---------------------------------------------------------------------------
__global__ __launch_bounds__(256) void convert_w(
    const float* __restrict__ W,
    unsigned short* __restrict__ Whi, unsigned short* __restrict__ Wlo)
{
  const int e = blockIdx.x;           // expert 0..255
  const int t = threadIdx.x;          // 0..255, use 224 (one BK=32 tile each)
  if (t >= 224) return;
  const int r = e & 127, bn = e >> 7;
  const float* src = W + (size_t)e * 7168 + t * 32;
  const size_t tbase = (size_t)(bn * 224 + t) * 4096 + (size_t)r * 32;
  #pragma unroll
  for (int g = 0; g < 4; ++g) {       // granule gi = g, k = g*8..g*8+7
    unsigned int hw[4], lw[4];
    #pragma unroll
    for (int p = 0; p < 4; ++p) {
      float f0 = src[g * 8 + 2 * p] * 64.0f;
      float f1 = src[g * 8 + 2 * p + 1] * 64.0f;
      unsigned short h0 = f2h(f0), h1 = f2h(f1);
      unsigned short l0 = f2h((f0 - h2f(h0)) * 2048.0f);
      unsigned short l1 = f2h((f1 - h2f(h1)) * 2048.0f);
      hw[p] = (unsigned)h0 | ((unsigned)h1 << 16);
      lw[p] = (unsigned)l0 | ((unsigned)l1 << 16);
    }
    const size_t base = tbase + (size_t)(swz(g, r) * 8);
    *(uint4*)(Whi + base) = make_uint4(hw[0], hw[1], hw[2], hw[3]);
    *(uint4*)(Wlo + base) = make_uint4(lw[0], lw[1], lw[2], lw[3]);
  }
}

// ---------------------------------------------------------------------------
// GEMM: BM=128, BN=128, BK=32, K-split KS. 256 threads = 4 waves (2x2),
// wave tile 64x64 = 2x2 frags of 32x32x16 f16 MFMA, 3 products.
// Double-buffered LDS (2 x 32KB). Per iter: issue glds B(s+1) -> issue
// A(s+2) loads (clamped; always 4 in flight) -> compute buf[cur]
// (setprio) -> convert/ds_write A(s+1) -> counted vmcnt(4) + s_barrier.
// Grid 1-D: ks = bid % KS (XCD-affine), bn = (bid/KS)&1, bm = bid/(2KS).
// ---------------------------------------------------------------------------
__global__ __launch_bounds__(256, 2) void gate_gemm(
    const float* __restrict__ X,
    const unsigned short* __restrict__ Whi,
    const unsigned short* __restrict__ Wlo,
    float* __restrict__ Spart, int D, int TILES, int KS)
{
  __shared__ char lds[65536];
  // buffer b at b*32768: Ahi +0 (8KB), Alo +8192, Bhi +16384, Blo +24576

  const int bid = blockIdx.x;
  const int ks = bid % KS;                 // XCD-affine for KS=8
  const int bn = (bid / KS) & 1;
  const int bm = bid / (2 * KS);
  const int tid = threadIdx.x, lane = tid & 63, wid = tid >> 6;
  const int wm = wid >> 1, wn = wid & 1;   // 2x2 wave grid
  const int TM = bm * 128;
  const int k0base = ks * TILES * 32;      // K-chunk start

  // A staging: 2 threads per row, 16 contiguous fp32 each
  const int srow = tid >> 1, skq = tid & 1;
  const float* xsrc = X + (size_t)(TM + srow) * D + k0base + skq * 16;
  const int aw0 = srow * 64 + swz(skq * 2 + 0, srow) * 16;
  const int aw1 = srow * 64 + swz(skq * 2 + 1, srow) * 16;

  const unsigned short* wh_tile = Whi + (size_t)(bn * 224 + ks * TILES) * 4096;
  const unsigned short* wl_tile = Wlo + (size_t)(bn * 224 + ks * TILES) * 4096;

  f32x16 acc1[2][2], acc2[2][2];
  #pragma unroll
  for (int m = 0; m < 2; ++m)
    #pragma unroll
    for (int n = 0; n < 2; ++n) { acc1[m][n] = (f32x16)0.0f; acc2[m][n] = (f32x16)0.0f; }

  // fragment read byte offsets, fixed per lane.
  // 32x32x16 A-frag: row = base + (lane&31), k = ks2*16 + (lane>>5)*8 + j
  //   -> granule gi = ks2*2 + (lane>>5), one swizzled 16B read.
  int aro[2][2], bro[2][2];
  const int gcol = lane >> 5;              // 0..1
  #pragma unroll
  for (int m = 0; m < 2; ++m) {
    const int row = wm * 64 + m * 32 + (lane & 31);
    #pragma unroll
    for (int k2 = 0; k2 < 2; ++k2)
      aro[m][k2] = row * 64 + swz(k2 * 2 + gcol, row) * 16;
  }
  #pragma unroll
  for (int n = 0; n < 2; ++n) {
    const int row = wn * 64 + n * 32 + (lane & 31);
    #pragma unroll
    for (int k2 = 0; k2 < 2; ++k2)
      bro[n][k2] = row * 64 + swz(k2 * 2 + gcol, row) * 16;
  }

  // ---- prologue: stage tile 0 into buf0; prefetch A(1) ----
  float4 pa[4], pb[4];
  {
    // glds first (oldest in vmcnt queue)
    #pragma unroll
    for (int i = 0; i < 2; ++i) {
      const int c = wid * 2 + i;          // chunk 0..7, wave-uniform
      glds16(wh_tile + c * 512 + lane * 8, lds + 16384 + c * 1024);
      glds16(wl_tile + c * 512 + lane * 8, lds + 24576 + c * 1024);
    }
    __builtin_amdgcn_sched_barrier(0);
    // A(0): load + convert + ds_write
    float4 a[4];
    #pragma unroll
    for (int i = 0; i < 4; ++i) a[i] = *(const float4*)(xsrc + i * 4);
    unsigned int hw[8], lw[8];
    #pragma unroll
    for (int q = 0; q < 8; ++q) {
      float f0 = ((const float*)a)[2 * q], f1 = ((const float*)a)[2 * q + 1];
      unsigned short h0 = f2h(f0), h1 = f2h(f1);
      unsigned short l0 = f2h((f0 - h2f(h0)) * 2048.0f);
      unsigned short l1 = f2h((f1 - h2f(h1)) * 2048.0f);
      hw[q] = (unsigned)h0 | ((unsigned)h1 << 16);
      lw[q] = (unsigned)l0 | ((unsigned)l1 << 16);
    }
    *(uint4*)(lds + aw0)        = make_uint4(hw[0], hw[1], hw[2], hw[3]);
    *(uint4*)(lds + aw1)        = make_uint4(hw[4], hw[5], hw[6], hw[7]);
    *(uint4*)(lds + 8192 + aw0) = make_uint4(lw[0], lw[1], lw[2], lw[3]);
    *(uint4*)(lds + 8192 + aw1) = make_uint4(lw[4], lw[5], lw[6], lw[7]);
    // prefetch A(1) (newest in queue)
    const int s1 = (TILES > 1) ? 1 : 0;
    #pragma unroll
    for (int i = 0; i < 4; ++i)
      pa[i] = *(const float4*)(xsrc + (size_t)s1 * 32 + i * 4);
    __builtin_amdgcn_sched_barrier(0);
  }
  asm volatile("s_waitcnt vmcnt(4) lgkmcnt(0)" ::: "memory");  // glds done, pa flying
  __builtin_amdgcn_sched_barrier(0);
  __builtin_amdgcn_s_barrier();

  int cur = 0;
  for (int s = 0; s < TILES; ++s) {
    const int nxt = cur ^ 1;
    char* base_c = lds + cur * 32768;
    char* base_n = lds + nxt * 32768;
    const bool stage_next = (s + 1 < TILES);

    // 1. issue glds B(s+1) (oldest vmem this tile)
    if (stage_next) {
      const unsigned short* wh = wh_tile + (size_t)(s + 1) * 4096;
      const unsigned short* wl = wl_tile + (size_t)(s + 1) * 4096;
      #pragma unroll
      for (int i = 0; i < 2; ++i) {
        const int c = wid * 2 + i;
        glds16(wh + c * 512 + lane * 8, base_n + 16384 + c * 1024);
        glds16(wl + c * 512 + lane * 8, base_n + 24576 + c * 1024);
      }
    }
    __builtin_amdgcn_sched_barrier(0);

    // 2. issue A(s+2) loads, clamped so exactly 4 are always in flight
    {
      int sn = s + 2; if (sn > TILES - 1) sn = TILES - 1;
      #pragma unroll
      for (int i = 0; i < 4; ++i)
        pb[i] = *(const float4*)(xsrc + (size_t)sn * 32 + i * 4);
    }
    __builtin_amdgcn_sched_barrier(0);

    // 3. compute from buf[cur]: 2x2 frags of 32x32x16, 3 products
    {
      const char* Ahi = base_c;          const char* Alo = base_c + 8192;
      const char* Bh  = base_c + 16384;  const char* Bl  = base_c + 24576;
      f16x8 ah[2][2], al[2][2], bh[2][2], bl[2][2];
      #pragma unroll
      for (int m = 0; m < 2; ++m)
        #pragma unroll
        for (int k2 = 0; k2 < 2; ++k2) {
          ah[m][k2] = *(const f16x8*)(Ahi + aro[m][k2]);
          al[m][k2] = *(const f16x8*)(Alo + aro[m][k2]);
        }
      #pragma unroll
      for (int n = 0; n < 2; ++n)
        #pragma unroll
        for (int k2 = 0; k2 < 2; ++k2) {
          bh[n][k2] = *(const f16x8*)(Bh + bro[n][k2]);
          bl[n][k2] = *(const f16x8*)(Bl + bro[n][k2]);
        }
      __builtin_amdgcn_s_setprio(1);
      #pragma unroll
      for (int k2 = 0; k2 < 2; ++k2)
        #pragma unroll
        for (int m = 0; m < 2; ++m)
          #pragma unroll
          for (int n = 0; n < 2; ++n) {
            acc1[m][n] = __builtin_amdgcn_mfma_f32_32x32x16_f16(ah[m][k2], bh[n][k2], acc1[m][n], 0, 0, 0);
            acc2[m][n] = __builtin_amdgcn_mfma_f32_32x32x16_f16(ah[m][k2], bl[n][k2], acc2[m][n], 0, 0, 0);
            acc2[m][n] = __builtin_amdgcn_mfma_f32_32x32x16_f16(al[m][k2], bh[n][k2], acc2[m][n], 0, 0, 0);
          }
      __builtin_amdgcn_s_setprio(0);
    }

    // 4. convert + ds_write A(s+1) into buf[nxt]
    if (stage_next) {
      unsigned int hw[8], lw[8];
      #pragma unroll
      for (int q = 0; q < 8; ++q) {
        float f0 = ((const float*)pa)[2 * q], f1 = ((const float*)pa)[2 * q + 1];
        unsigned short h0 = f2h(f0), h1 = f2h(f1);
        unsigned short l0 = f2h((f0 - h2f(h0)) * 2048.0f);
        unsigned short l1 = f2h((f1 - h2f(h1)) * 2048.0f);
        hw[q] = (unsigned)h0 | ((unsigned)h1 << 16);
        lw[q] = (unsigned)l0 | ((unsigned)l1 << 16);
      }
      *(uint4*)(base_n + aw0)        = make_uint4(hw[0], hw[1], hw[2], hw[3]);
      *(uint4*)(base_n + aw1)        = make_uint4(hw[4], hw[5], hw[6], hw[7]);
      *(uint4*)(base_n + 8192 + aw0) = make_uint4(lw[0], lw[1], lw[2], lw[3]);
      *(uint4*)(base_n + 8192 + aw1) = make_uint4(lw[4], lw[5], lw[6], lw[7]);
    }
    #pragma unroll
    for (int i = 0; i < 4; ++i) pa[i] = pb[i];

    // 5. counted drain + raw barrier: glds(s+1) done, A(s+2) stays in flight
    asm volatile("s_waitcnt vmcnt(4) lgkmcnt(0)" ::: "memory");
    __builtin_amdgcn_sched_barrier(0);
    __builtin_amdgcn_s_barrier();

    cur = nxt;
  }

  // epilogue: logit partial = (acc1 + acc2/2048) / 64
  // 32x32 C/D layout (m74/m101): col=lane&31, row=(reg&3)+8*(reg>>2)+4*(lane>>5)
  float* Sp = Spart + (size_t)ks * 8192 * 256;
  #pragma unroll
  for (int m = 0; m < 2; ++m)
    #pragma unroll
    for (int n = 0; n < 2; ++n)
      #pragma unroll
      for (int r = 0; r < 16; ++r) {
        const int rowf = (r & 3) + 8 * (r >> 2) + 4 * (lane >> 5);
        const int t = TM + wm * 64 + m * 32 + rowf;
        const int e = bn * 128 + wn * 64 + n * 32 + (lane & 31);
        Sp[(size_t)t * 256 + e] =
            (acc1[m][n][r] + acc2[m][n][r] * (1.0f / 2048.0f)) * (1.0f / 64.0f);
      }
}

// ---------------------------------------------------------------------------
// Routing: one wave per token. logit = sum of KS fp32 partials in DOUBLE
// (exact); scores = sigmoid (fp32); then grouped top-k (8 groups, top-2
// group score, top-4 groups, top-8 experts, renorm * 2.5).
// ---------------------------------------------------------------------------
__global__ __launch_bounds__(256) void gate_routing(
    const float* __restrict__ Spart, int KS,
    const float* __restrict__ bias,
    float* __restrict__ outw, float* __restrict__ outi, int T)
{
  const int lane = threadIdx.x & 63;
  const int wave = threadIdx.x >> 6;
  const int t = blockIdx.x * 4 + wave;
  if (t >= T) return;

  double l[4] = {0.0, 0.0, 0.0, 0.0};
  for (int ks = 0; ks < KS; ++ks) {
    float4 p = *(const float4*)(Spart + (size_t)ks * T * 256
                                + (size_t)t * 256 + lane * 4);
    l[0] += (double)p.x; l[1] += (double)p.y;
    l[2] += (double)p.z; l[3] += (double)p.w;
  }

  float4 bi = *(const float4*)(bias + lane * 4);
  float orig[4], s[4];
  #pragma unroll
  for (int u = 0; u < 4; ++u)
    orig[u] = 1.0f / (1.0f + expf(-(float)l[u]));
  s[0] = orig[0] + bi.x; s[1] = orig[1] + bi.y;
  s[2] = orig[2] + bi.z; s[3] = orig[3] + bi.w;

  // per-lane top-2 of its 4 biased scores
  float m1 = -INFINITY, m2 = -INFINITY;
  #pragma unroll
  for (int u = 0; u < 4; ++u) {
    float v = s[u];
    if (v > m1) { m2 = m1; m1 = v; }
    else if (v > m2) { m2 = v; }
  }
  // merge top-2 across the 8 lanes of the group
  #pragma unroll
  for (int off = 1; off < 8; off <<= 1) {
    float o1 = __shfl_xor(m1, off, 64);
    float o2 = __shfl_xor(m2, off, 64);
    if (o1 > m1) { m2 = fmaxf(m1, o2); m1 = o1; }
    else         { m2 = fmaxf(m2, o1); }
  }
  const float gscore = m1 + m2;

  const int g = lane >> 3;
  int rank = 0;
  #pragma unroll
  for (int j = 0; j < 8; ++j) {
    float gs = __shfl(gscore, j * 8, 64);
    rank += (gs > gscore || (gs == gscore && j < g)) ? 1 : 0;
  }
  if (rank >= 4) { s[0] = s[1] = s[2] = s[3] = -INFINITY; }

  float wsum = 0.0f, sel_w = 0.0f;
  int sel_i = 0;
  #pragma unroll
  for (int it = 0; it < 8; ++it) {
    float bv = s[0]; int bu = 0;
    #pragma unroll
    for (int u = 1; u < 4; ++u)
      if (s[u] > bv) { bv = s[u]; bu = u; }
    float v = bv;
    int ix = lane * 4 + bu;
    float og = orig[bu];
    #pragma unroll
    for (int off = 1; off < 64; off <<= 1) {
      float ov  = __shfl_xor(v,  off, 64);
      int   oix = __shfl_xor(ix, off, 64);
      float oog = __shfl_xor(og, off, 64);
      if (ov > v || (ov == v && oix < ix)) { v = ov; ix = oix; og = oog; }
    }
    if (lane == it) { sel_w = og; sel_i = ix; }
    wsum += og;
    if ((ix >> 2) == lane) s[ix & 3] = -INFINITY;
  }

  if (lane < 8) {
    outw[(size_t)t * 8 + lane] = sel_w / wsum * 2.5f;
    outi[(size_t)t * 8 + lane] = (float)sel_i;
  }
}

extern "C" void kernel_launch(void* const* d_in, const int* in_sizes, int n_in,
                              void* d_out, int out_size, void* d_ws, size_t ws_size,
                              hipStream_t stream) {
  const float* x = (const float*)d_in[0];
  const float* w = (const float*)d_in[1];
  const float* b = (const float*)d_in[2];
  const int E = in_sizes[2];                  // 256
  const int D = in_sizes[1] / E;              // 7168
  const int T = in_sizes[0] / D;              // 8192

  unsigned short* Whi = (unsigned short*)d_ws;                       // 3.67 MB
  unsigned short* Wlo = (unsigned short*)((char*)d_ws + (4u << 20)); // 3.67 MB
  float* Spart = (float*)((char*)d_ws + (8u << 20));                 // KS x 8 MB

  // adaptive K-split: largest of {8,4,2} that fits the workspace
  const size_t per_part = (size_t)T * E * 4;
  int KS = 2;
  if (ws_size >= (8u << 20) + 8 * per_part) KS = 8;
  else if (ws_size >= (8u << 20) + 4 * per_part) KS = 4;
  const int TILES = D / (32 * KS);            // 28 for KS=8

  float* outw = (float*)d_out;
  float* outi = outw + (size_t)T * 8;

  convert_w<<<E, 256, 0, stream>>>(w, Whi, Wlo);
  // 1-D grid, ks fastest (XCD-affine for KS=8): 2*KS*(T/128) blocks
  gate_gemm<<<2 * KS * (T / 128), 256, 0, stream>>>(x, Whi, Wlo, Spart, D, TILES, KS);
  gate_routing<<<(T + 3) / 4, 256, 0, stream>>>(Spart, KS, b, outw, outi, T);
}

// Round 16
// 137.266 us; speedup vs baseline: 2.5672x; 1.1614x over previous
//
#include <hip/hip_runtime.h>
#include <hip/hip_bf16.h>
#include <math.h>

// ---------------------------------------------------------------------------
// MoE gate via fp16 hi/lo split MFMA, 3 products (validated round 5):
//   x = xh + xl/2048,  W*64 = wh + wl/2048
//   logit = ( xh·wh + (xh·wl + xl·wh)/2048 ) / 64
// Round 16 = round 11 schedule with BN=256 (bn split removed):
//   - each X element converted ONCE (VALU convert halves: 8 fp32/thr/tile)
//   - X re-read across bn eliminated
//   - LDS buffer 40KB {Ahi 4K|Alo 4K|Bhi 16K|Blo 16K}, dbuf 80KB ->
//     2 blocks/CU at exactly the 160KiB limit
//   - B from r9-validated 256-row pre-swizzled tiles via glds
// Numerics / counted-vmcnt / XCD-affine ks / routing identical to r11.
// ---------------------------------------------------------------------------

typedef _Float16 f16x8 __attribute__((ext_vector_type(8)));
typedef float    f32x4 __attribute__((ext_vector_type(4)));

__device__ __forceinline__ void glds16(const void* g, void* l) {
  __builtin_amdgcn_global_load_lds(
      (const __attribute__((address_space(1))) void*)g,
      (__attribute__((address_space(3))) void*)l, 16, 0, 0);
}

__device__ __forceinline__ unsigned short f2h(float f) {
  _Float16 h = (_Float16)f;                       // v_cvt_f16_f32, RTN
  return __builtin_bit_cast(unsigned short, h);
}
__device__ __forceinline__ float h2f(unsigned short b) {
  return (float)__builtin_bit_cast(_Float16, b);
}

// swizzle: 64B rows, 4 granules of 16B; bijective in gi per row.
__device__ __forceinline__ int swz(int gi, int row) {
  return gi ^ (row & 3) ^ ((row >> 2) & 3);
}

// ---------------------------------------------------------------------------
// W [256][7168] fp32 -> Whi/Wlo fp16, 256-row pre-swizzled K-tiles (BK=32):
// K-tile t in 0..223 = 256 rows x 32 f16 = 8192 ushorts (16KB).
// element (r,k): gi=k>>3, addr = t*8192 + r*32 + swz(gi,r)*8 + (k&7).
// Whi = fp16(64*W); Wlo = fp16((64*W - Whi) * 2048).   (validated r9/r10)
// ---------------------------------------------------------------------------
__global__ __launch_bounds__(256) void convert_w(
    const float* __restrict__ W,
    unsigned short* __restrict__ Whi, unsigned short* __restrict__ Wlo)
{
  const int e = blockIdx.x;           // expert/row 0..255
  const int t = threadIdx.x;          // 0..255, use 224 (one K-tile each)
  if (t >= 224) return;
  const float* src = W + (size_t)e * 7168 + t * 32;
  const size_t tbase = (size_t)t * 8192 + (size_t)e * 32;
  #pragma unroll
  for (int g = 0; g < 4; ++g) {       // granule gi = g, k = g*8..g*8+7
    unsigned int hw[4], lw[4];
    #pragma unroll
    for (int p = 0; p < 4; ++p) {
      float f0 = src[g * 8 + 2 * p] * 64.0f;
      float f1 = src[g * 8 + 2 * p + 1] * 64.0f;
      unsigned short h0 = f2h(f0), h1 = f2h(f1);
      unsigned short l0 = f2h((f0 - h2f(h0)) * 2048.0f);
      unsigned short l1 = f2h((f1 - h2f(h1)) * 2048.0f);
      hw[p] = (unsigned)h0 | ((unsigned)h1 << 16);
      lw[p] = (unsigned)l0 | ((unsigned)l1 << 16);
    }
    const size_t base = tbase + (size_t)(swz(g, e) * 8);
    *(uint4*)(Whi + base) = make_uint4(hw[0], hw[1], hw[2], hw[3]);
    *(uint4*)(Wlo + base) = make_uint4(lw[0], lw[1], lw[2], lw[3]);
  }
}

// ---------------------------------------------------------------------------
// GEMM: BM=64, BN=256, BK=32, K-split KS. 256 threads = 4 waves (1x4),
// wave tile 64x64 = 4x4 frags of 16x16x32 f16 MFMA, 3 products.
// Double-buffered LDS (2 x 40KB = 80KB -> 2 blocks/CU). Per iter: issue
// glds B(s+1) (8/wave) -> issue A(s+2) loads (2/thread, clamped) ->
// compute buf[cur] (setprio) -> convert/ds_write A(s+1) -> vmcnt(2) +
// s_barrier.  Grid 1-D: ks = bid % KS (XCD-affine), bm = bid / KS.
// ---------------------------------------------------------------------------
#define BUF_SZ   40960
#define O_ALO    4096
#define O_BH     8192
#define O_BL     24576

__global__ __launch_bounds__(256, 2) void gate_gemm(
    const float* __restrict__ X,
    const unsigned short* __restrict__ Whi,
    const unsigned short* __restrict__ Wlo,
    float* __restrict__ Spart, int D, int TILES, int KS)
{
  __shared__ char lds[81920];

  const int bid = blockIdx.x;
  const int ks = bid % KS;                 // XCD-affine for KS=8
  const int bm = bid / KS;
  const int tid = threadIdx.x, lane = tid & 63, wid = tid >> 6;
  const int wn = wid;                      // 1M x 4N wave grid
  const int TM = bm * 64;
  const int k0base = ks * TILES * 32;      // K-chunk start

  // A staging: 4 threads per row, 8 contiguous fp32 each (one granule)
  const int srow = tid >> 2, sg = tid & 3;
  const float* xsrc = X + (size_t)(TM + srow) * D + k0base + sg * 8;
  const int aw = srow * 64 + swz(sg, srow) * 16;   // byte offset

  const unsigned short* wh_tile = Whi + (size_t)(ks * TILES) * 8192;
  const unsigned short* wl_tile = Wlo + (size_t)(ks * TILES) * 8192;

  f32x4 acc1[4][4], acc2[4][4];
  #pragma unroll
  for (int m = 0; m < 4; ++m)
    #pragma unroll
    for (int n = 0; n < 4; ++n) { acc1[m][n] = (f32x4)0.0f; acc2[m][n] = (f32x4)0.0f; }

  // fragment read byte offsets, fixed per lane
  int aro[4], bro[4];
  const int gi = lane >> 4;
  #pragma unroll
  for (int m = 0; m < 4; ++m) {
    const int row = m * 16 + (lane & 15);
    aro[m] = row * 64 + swz(gi, row) * 16;
  }
  #pragma unroll
  for (int n = 0; n < 4; ++n) {
    const int row = wn * 64 + n * 16 + (lane & 15);
    bro[n] = row * 64 + swz(gi, row) * 16;
  }

  // ---- prologue: stage tile 0 into buf0; prefetch A(1) ----
  float4 pa0, pa1, pb0, pb1;
  {
    // glds first (oldest in vmcnt queue): 4 hi + 4 lo chunks per wave
    #pragma unroll
    for (int i = 0; i < 4; ++i) {
      const int c = wid * 4 + i;          // chunk 0..15, wave-uniform
      glds16(wh_tile + c * 512 + lane * 8, lds + O_BH + c * 1024);
      glds16(wl_tile + c * 512 + lane * 8, lds + O_BL + c * 1024);
    }
    __builtin_amdgcn_sched_barrier(0);
    // A(0): load + convert + ds_write
    float4 a0 = *(const float4*)(xsrc);
    float4 a1 = *(const float4*)(xsrc + 4);
    float ff[8] = {a0.x, a0.y, a0.z, a0.w, a1.x, a1.y, a1.z, a1.w};
    unsigned int hw[4], lw[4];
    #pragma unroll
    for (int q = 0; q < 4; ++q) {
      float f0 = ff[2 * q], f1 = ff[2 * q + 1];
      unsigned short h0 = f2h(f0), h1 = f2h(f1);
      unsigned short l0 = f2h((f0 - h2f(h0)) * 2048.0f);
      unsigned short l1 = f2h((f1 - h2f(h1)) * 2048.0f);
      hw[q] = (unsigned)h0 | ((unsigned)h1 << 16);
      lw[q] = (unsigned)l0 | ((unsigned)l1 << 16);
    }
    *(uint4*)(lds + aw)         = make_uint4(hw[0], hw[1], hw[2], hw[3]);
    *(uint4*)(lds + O_ALO + aw) = make_uint4(lw[0], lw[1], lw[2], lw[3]);
    // prefetch A(1) (newest in queue)
    const int s1 = (TILES > 1) ? 1 : 0;
    pa0 = *(const float4*)(xsrc + (size_t)s1 * 32);
    pa1 = *(const float4*)(xsrc + (size_t)s1 * 32 + 4);
    __builtin_amdgcn_sched_barrier(0);
  }
  asm volatile("s_waitcnt vmcnt(2) lgkmcnt(0)" ::: "memory");  // glds done, pa flying
  __builtin_amdgcn_sched_barrier(0);
  __builtin_amdgcn_s_barrier();

  int cur = 0;
  for (int s = 0; s < TILES; ++s) {
    const int nxt = cur ^ 1;
    char* base_c = lds + cur * BUF_SZ;
    char* base_n = lds + nxt * BUF_SZ;
    const bool stage_next = (s + 1 < TILES);

    // 1. issue glds B(s+1) (oldest vmem this tile)
    if (stage_next) {
      const unsigned short* wh = wh_tile + (size_t)(s + 1) * 8192;
      const unsigned short* wl = wl_tile + (size_t)(s + 1) * 8192;
      #pragma unroll
      for (int i = 0; i < 4; ++i) {
        const int c = wid * 4 + i;
        glds16(wh + c * 512 + lane * 8, base_n + O_BH + c * 1024);
        glds16(wl + c * 512 + lane * 8, base_n + O_BL + c * 1024);
      }
    }
    __builtin_amdgcn_sched_barrier(0);

    // 2. issue A(s+2) loads, clamped so exactly 2 are always in flight
    {
      int sn = s + 2; if (sn > TILES - 1) sn = TILES - 1;
      pb0 = *(const float4*)(xsrc + (size_t)sn * 32);
      pb1 = *(const float4*)(xsrc + (size_t)sn * 32 + 4);
    }
    __builtin_amdgcn_sched_barrier(0);

    // 3. compute from buf[cur]
    {
      const char* Ahi = base_c;         const char* Alo = base_c + O_ALO;
      const char* Bh  = base_c + O_BH;  const char* Bl  = base_c + O_BL;
      f16x8 ah[4], al[4], bh[4], bl[4];
      #pragma unroll
      for (int m = 0; m < 4; ++m) {
        ah[m] = *(const f16x8*)(Ahi + aro[m]);
        al[m] = *(const f16x8*)(Alo + aro[m]);
      }
      #pragma unroll
      for (int n = 0; n < 4; ++n) {
        bh[n] = *(const f16x8*)(Bh + bro[n]);
        bl[n] = *(const f16x8*)(Bl + bro[n]);
      }
      __builtin_amdgcn_s_setprio(1);
      #pragma unroll
      for (int m = 0; m < 4; ++m)
        #pragma unroll
        for (int n = 0; n < 4; ++n) {
          acc1[m][n] = __builtin_amdgcn_mfma_f32_16x16x32_f16(ah[m], bh[n], acc1[m][n], 0, 0, 0);
          acc2[m][n] = __builtin_amdgcn_mfma_f32_16x16x32_f16(ah[m], bl[n], acc2[m][n], 0, 0, 0);
          acc2[m][n] = __builtin_amdgcn_mfma_f32_16x16x32_f16(al[m], bh[n], acc2[m][n], 0, 0, 0);
        }
      __builtin_amdgcn_s_setprio(0);
    }

    // 4. convert + ds_write A(s+1) into buf[nxt]
    if (stage_next) {
      float ff[8] = {pa0.x, pa0.y, pa0.z, pa0.w, pa1.x, pa1.y, pa1.z, pa1.w};
      unsigned int hw[4], lw[4];
      #pragma unroll
      for (int q = 0; q < 4; ++q) {
        float f0 = ff[2 * q], f1 = ff[2 * q + 1];
        unsigned short h0 = f2h(f0), h1 = f2h(f1);
        unsigned short l0 = f2h((f0 - h2f(h0)) * 2048.0f);
        unsigned short l1 = f2h((f1 - h2f(h1)) * 2048.0f);
        hw[q] = (unsigned)h0 | ((unsigned)h1 << 16);
        lw[q] = (unsigned)l0 | ((unsigned)l1 << 16);
      }
      *(uint4*)(base_n + aw)         = make_uint4(hw[0], hw[1], hw[2], hw[3]);
      *(uint4*)(base_n + O_ALO + aw) = make_uint4(lw[0], lw[1], lw[2], lw[3]);
    }
    pa0 = pb0; pa1 = pb1;

    // 5. counted drain + raw barrier: glds(s+1) done, A(s+2) stays in flight
    asm volatile("s_waitcnt vmcnt(2) lgkmcnt(0)" ::: "memory");
    __builtin_amdgcn_sched_barrier(0);
    __builtin_amdgcn_s_barrier();

    cur = nxt;
  }

  // epilogue: logit partial = (acc1 + acc2/2048) / 64
  // C/D layout: col=lane&15, row=(lane>>4)*4+reg
  float* Sp = Spart + (size_t)ks * 8192 * 256;
  #pragma unroll
  for (int m = 0; m < 4; ++m)
    #pragma unroll
    for (int n = 0; n < 4; ++n)
      #pragma unroll
      for (int r = 0; r < 4; ++r) {
        const int t = TM + m * 16 + (lane >> 4) * 4 + r;
        const int e = wn * 64 + n * 16 + (lane & 15);
        Sp[(size_t)t * 256 + e] =
            (acc1[m][n][r] + acc2[m][n][r] * (1.0f / 2048.0f)) * (1.0f / 64.0f);
      }
}

// ---------------------------------------------------------------------------
// Routing: one wave per token. logit = sum of KS fp32 partials in DOUBLE
// (exact); scores = sigmoid (fp32); then grouped top-k (8 groups, top-2
// group score, top-4 groups, top-8 experts, renorm * 2.5).
// ---------------------------------------------------------------------------
__global__ __launch_bounds__(256) void gate_routing(
    const float* __restrict__ Spart, int KS,
    const float* __restrict__ bias,
    float* __restrict__ outw, float* __restrict__ outi, int T)
{
  const int lane = threadIdx.x & 63;
  const int wave = threadIdx.x >> 6;
  const int t = blockIdx.x * 4 + wave;
  if (t >= T) return;

  double l[4] = {0.0, 0.0, 0.0, 0.0};
  for (int ks = 0; ks < KS; ++ks) {
    float4 p = *(const float4*)(Spart + (size_t)ks * T * 256
                                + (size_t)t * 256 + lane * 4);
    l[0] += (double)p.x; l[1] += (double)p.y;
    l[2] += (double)p.z; l[3] += (double)p.w;
  }

  float4 bi = *(const float4*)(bias + lane * 4);
  float orig[4], s[4];
  #pragma unroll
  for (int u = 0; u < 4; ++u)
    orig[u] = 1.0f / (1.0f + expf(-(float)l[u]));
  s[0] = orig[0] + bi.x; s[1] = orig[1] + bi.y;
  s[2] = orig[2] + bi.z; s[3] = orig[3] + bi.w;

  // per-lane top-2 of its 4 biased scores
  float m1 = -INFINITY, m2 = -INFINITY;
  #pragma unroll
  for (int u = 0; u < 4; ++u) {
    float v = s[u];
    if (v > m1) { m2 = m1; m1 = v; }
    else if (v > m2) { m2 = v; }
  }
  // merge top-2 across the 8 lanes of the group
  #pragma unroll
  for (int off = 1; off < 8; off <<= 1) {
    float o1 = __shfl_xor(m1, off, 64);
    float o2 = __shfl_xor(m2, off, 64);
    if (o1 > m1) { m2 = fmaxf(m1, o2); m1 = o1; }
    else         { m2 = fmaxf(m2, o1); }
  }
  const float gscore = m1 + m2;

  const int g = lane >> 3;
  int rank = 0;
  #pragma unroll
  for (int j = 0; j < 8; ++j) {
    float gs = __shfl(gscore, j * 8, 64);
    rank += (gs > gscore || (gs == gscore && j < g)) ? 1 : 0;
  }
  if (rank >= 4) { s[0] = s[1] = s[2] = s[3] = -INFINITY; }

  float wsum = 0.0f, sel_w = 0.0f;
  int sel_i = 0;
  #pragma unroll
  for (int it = 0; it < 8; ++it) {
    float bv = s[0]; int bu = 0;
    #pragma unroll
    for (int u = 1; u < 4; ++u)
      if (s[u] > bv) { bv = s[u]; bu = u; }
    float v = bv;
    int ix = lane * 4 + bu;
    float og = orig[bu];
    #pragma unroll
    for (int off = 1; off < 64; off <<= 1) {
      float ov  = __shfl_xor(v,  off, 64);
      int   oix = __shfl_xor(ix, off, 64);
      float oog = __shfl_xor(og, off, 64);
      if (ov > v || (ov == v && oix < ix)) { v = ov; ix = oix; og = oog; }
    }
    if (lane == it) { sel_w = og; sel_i = ix; }
    wsum += og;
    if ((ix >> 2) == lane) s[ix & 3] = -INFINITY;
  }

  if (lane < 8) {
    outw[(size_t)t * 8 + lane] = sel_w / wsum * 2.5f;
    outi[(size_t)t * 8 + lane] = (float)sel_i;
  }
}

extern "C" void kernel_launch(void* const* d_in, const int* in_sizes, int n_in,
                              void* d_out, int out_size, void* d_ws, size_t ws_size,
                              hipStream_t stream) {
  const float* x = (const float*)d_in[0];
  const float* w = (const float*)d_in[1];
  const float* b = (const float*)d_in[2];
  const int E = in_sizes[2];                  // 256
  const int D = in_sizes[1] / E;              // 7168
  const int T = in_sizes[0] / D;              // 8192

  unsigned short* Whi = (unsigned short*)d_ws;                       // 3.67 MB
  unsigned short* Wlo = (unsigned short*)((char*)d_ws + (4u << 20)); // 3.67 MB
  float* Spart = (float*)((char*)d_ws + (8u << 20));                 // KS x 8 MB

  // adaptive K-split: largest of {8,4,2} that fits the workspace
  const size_t per_part = (size_t)T * E * 4;
  int KS = 2;
  if (ws_size >= (8u << 20) + 8 * per_part) KS = 8;
  else if (ws_size >= (8u << 20) + 4 * per_part) KS = 4;
  const int TILES = D / (32 * KS);            // 28 for KS=8

  float* outw = (float*)d_out;
  float* outi = outw + (size_t)T * 8;

  convert_w<<<E, 256, 0, stream>>>(w, Whi, Wlo);
  // 1-D grid, ks fastest (XCD-affine for KS=8): KS*(T/64) blocks
  gate_gemm<<<KS * (T / 64), 256, 0, stream>>>(x, Whi, Wlo, Spart, D, TILES, KS);
  gate_routing<<<(T + 3) / 4, 256, 0, stream>>>(Spart, KS, b, outw, outi, T);
}

// Round 17
// 134.522 us; speedup vs baseline: 2.6196x; 1.0204x over previous
//
#include <hip/hip_runtime.h>
#include <hip/hip_bf16.h>
#include <math.h>

// ---------------------------------------------------------------------------
// MoE gate via fp16 hi/lo split MFMA, 3 products (validated round 5):
//   x = xh + xl/2048,  W*64 = wh + wl/2048
//   logit = ( xh·wh + (xh·wl + xl·wh)/2048 ) / 64
// Round 17 = round 16 (137us, best) with LDS-traffic halved:
//   BM=128, BN=256, 512 thr / 8 waves (2Mx4N), wave tile 64x64 -> one
//   block covers what two r16 blocks did, halving per-work LDS bytes
//   (208KB -> 112KB per 128x256x32 tile).
//   1 block/CU; barrier exposure fixed by TRIPLE-buffered LDS (3x48KB)
//   with glds issued TWO tiles ahead (full-tile latency coverage) and
//   counted vmcnt(6) (4 glds + 2 pa per wave per tile stay in flight).
// Numerics / layouts / convert_w / routing identical to r16 (passed).
// ---------------------------------------------------------------------------

typedef _Float16 f16x8 __attribute__((ext_vector_type(8)));
typedef float    f32x4 __attribute__((ext_vector_type(4)));

__device__ __forceinline__ void glds16(const void* g, void* l) {
  __builtin_amdgcn_global_load_lds(
      (const __attribute__((address_space(1))) void*)g,
      (__attribute__((address_space(3))) void*)l, 16, 0, 0);
}

__device__ __forceinline__ unsigned short f2h(float f) {
  _Float16 h = (_Float16)f;                       // v_cvt_f16_f32, RTN
  return __builtin_bit_cast(unsigned short, h);
}
__device__ __forceinline__ float h2f(unsigned short b) {
  return (float)__builtin_bit_cast(_Float16, b);
}

// swizzle: 64B rows, 4 granules of 16B; bijective in gi per row.
__device__ __forceinline__ int swz(int gi, int row) {
  return gi ^ (row & 3) ^ ((row >> 2) & 3);
}

// ---------------------------------------------------------------------------
// W [256][7168] fp32 -> Whi/Wlo fp16, 256-row pre-swizzled K-tiles (BK=32):
// K-tile t in 0..223 = 256 rows x 32 f16 = 8192 ushorts (16KB).
// element (r,k): gi=k>>3, addr = t*8192 + r*32 + swz(gi,r)*8 + (k&7).
// Whi = fp16(64*W); Wlo = fp16((64*W - Whi) * 2048).   (validated r9/r16)
// ---------------------------------------------------------------------------
__global__ __launch_bounds__(256) void convert_w(
    const float* __restrict__ W,
    unsigned short* __restrict__ Whi, unsigned short* __restrict__ Wlo)
{
  const int e = blockIdx.x;           // expert/row 0..255
  const int t = threadIdx.x;          // 0..255, use 224 (one K-tile each)
  if (t >= 224) return;
  const float* src = W + (size_t)e * 7168 + t * 32;
  const size_t tbase = (size_t)t * 8192 + (size_t)e * 32;
  #pragma unroll
  for (int g = 0; g < 4; ++g) {       // granule gi = g, k = g*8..g*8+7
    unsigned int hw[4], lw[4];
    #pragma unroll
    for (int p = 0; p < 4; ++p) {
      float f0 = src[g * 8 + 2 * p] * 64.0f;
      float f1 = src[g * 8 + 2 * p + 1] * 64.0f;
      unsigned short h0 = f2h(f0), h1 = f2h(f1);
      unsigned short l0 = f2h((f0 - h2f(h0)) * 2048.0f);
      unsigned short l1 = f2h((f1 - h2f(h1)) * 2048.0f);
      hw[p] = (unsigned)h0 | ((unsigned)h1 << 16);
      lw[p] = (unsigned)l0 | ((unsigned)l1 << 16);
    }
    const size_t base = tbase + (size_t)(swz(g, e) * 8);
    *(uint4*)(Whi + base) = make_uint4(hw[0], hw[1], hw[2], hw[3]);
    *(uint4*)(Wlo + base) = make_uint4(lw[0], lw[1], lw[2], lw[3]);
  }
}

// ---------------------------------------------------------------------------
// GEMM: BM=128, BN=256, BK=32, K-split KS. 512 threads = 8 waves (2Mx4N),
// wave tile 64x64 = 4x4 frags of 16x16x32 f16 MFMA, 3 products.
// TRIPLE-buffered LDS (3 x 48KB = 144KB). Per tile s:
//   1. issue glds B(s+2) -> buf[(s+2)%3]   (4 glds/wave, 2 tiles ahead)
//   2. issue A(s+2) loads (2/thread, clamped)
//   3. compute buf[s%3] (setprio)
//   4. convert pa(s+1) -> ds_write A -> buf[(s+1)%3]
//   5. vmcnt(6) + lgkmcnt(0) + s_barrier   (glds(s+2)+pa(s+2) in flight)
// Grid 1-D: ks = bid % KS (XCD-affine), bm = bid / KS.
// ---------------------------------------------------------------------------
#define BUF_SZ   49152
#define O_ALO    8192
#define O_BH     16384
#define O_BL     32768

__global__ __launch_bounds__(512, 2) void gate_gemm(
    const float* __restrict__ X,
    const unsigned short* __restrict__ Whi,
    const unsigned short* __restrict__ Wlo,
    float* __restrict__ Spart, int D, int TILES, int KS)
{
  __shared__ char lds[147456];   // 3 buffers

  const int bid = blockIdx.x;
  const int ks = bid % KS;                 // XCD-affine for KS=8
  const int bm = bid / KS;
  const int tid = threadIdx.x, lane = tid & 63, wid = tid >> 6;
  const int wm = wid >> 2, wn = wid & 3;   // 2M x 4N wave grid
  const int TM = bm * 128;
  const int k0base = ks * TILES * 32;      // K-chunk start

  // A staging: 4 threads per row, 8 contiguous fp32 each (one granule)
  const int srow = tid >> 2, sg = tid & 3;
  const float* xsrc = X + (size_t)(TM + srow) * D + k0base + sg * 8;
  const int aw = srow * 64 + swz(sg, srow) * 16;   // byte offset

  const unsigned short* wh_tile = Whi + (size_t)(ks * TILES) * 8192;
  const unsigned short* wl_tile = Wlo + (size_t)(ks * TILES) * 8192;

  f32x4 acc1[4][4], acc2[4][4];
  #pragma unroll
  for (int m = 0; m < 4; ++m)
    #pragma unroll
    for (int n = 0; n < 4; ++n) { acc1[m][n] = (f32x4)0.0f; acc2[m][n] = (f32x4)0.0f; }

  // fragment read byte offsets, fixed per lane
  int aro[4], bro[4];
  const int gi = lane >> 4;
  #pragma unroll
  for (int m = 0; m < 4; ++m) {
    const int row = wm * 64 + m * 16 + (lane & 15);
    aro[m] = row * 64 + swz(gi, row) * 16;
  }
  #pragma unroll
  for (int n = 0; n < 4; ++n) {
    const int row = wn * 64 + n * 16 + (lane & 15);
    bro[n] = row * 64 + swz(gi, row) * 16;
  }

  // ---- prologue: A(0) loads first, stage B(0)->buf0, B(1)->buf1,
  //      A(0) convert+write, prefetch pa(1) ----
  float4 pa0, pa1, pb0, pb1;
  {
    float4 a0 = *(const float4*)(xsrc);          // oldest in queue
    float4 a1 = *(const float4*)(xsrc + 4);
    #pragma unroll
    for (int i = 0; i < 2; ++i) {                // glds B(0) (4/wave)
      const int c = wid * 2 + i;                 // chunk 0..15, wave-uniform
      glds16(wh_tile + c * 512 + lane * 8, lds + O_BH + c * 1024);
      glds16(wl_tile + c * 512 + lane * 8, lds + O_BL + c * 1024);
    }
    if (TILES > 1) {                             // glds B(1) (4/wave)
      #pragma unroll
      for (int i = 0; i < 2; ++i) {
        const int c = wid * 2 + i;
        glds16(wh_tile + 8192 + c * 512 + lane * 8, lds + BUF_SZ + O_BH + c * 1024);
        glds16(wl_tile + 8192 + c * 512 + lane * 8, lds + BUF_SZ + O_BL + c * 1024);
      }
    }
    __builtin_amdgcn_sched_barrier(0);
    // prefetch pa(1) (newest)
    const int s1 = (TILES > 1) ? 1 : 0;
    pa0 = *(const float4*)(xsrc + (size_t)s1 * 32);
    pa1 = *(const float4*)(xsrc + (size_t)s1 * 32 + 4);
    __builtin_amdgcn_sched_barrier(0);
    // convert + write A(0) into buf0 (compiler waits a0/a1 here)
    float ff[8] = {a0.x, a0.y, a0.z, a0.w, a1.x, a1.y, a1.z, a1.w};
    unsigned int hw[4], lw[4];
    #pragma unroll
    for (int q = 0; q < 4; ++q) {
      float f0 = ff[2 * q], f1 = ff[2 * q + 1];
      unsigned short h0 = f2h(f0), h1 = f2h(f1);
      unsigned short l0 = f2h((f0 - h2f(h0)) * 2048.0f);
      unsigned short l1 = f2h((f1 - h2f(h1)) * 2048.0f);
      hw[q] = (unsigned)h0 | ((unsigned)h1 << 16);
      lw[q] = (unsigned)l0 | ((unsigned)l1 << 16);
    }
    *(uint4*)(lds + aw)         = make_uint4(hw[0], hw[1], hw[2], hw[3]);
    *(uint4*)(lds + O_ALO + aw) = make_uint4(lw[0], lw[1], lw[2], lw[3]);
    __builtin_amdgcn_sched_barrier(0);
  }
  // B(0) done: after-glds(0) items = glds(1) 4 + pa(1) 2 = 6
  asm volatile("s_waitcnt vmcnt(6) lgkmcnt(0)" ::: "memory");
  __builtin_amdgcn_sched_barrier(0);
  __builtin_amdgcn_s_barrier();

  for (int s = 0; s < TILES; ++s) {
    char* base_c  = lds + (s % 3) * BUF_SZ;
    char* base_n1 = lds + ((s + 1) % 3) * BUF_SZ;
    char* base_n2 = lds + ((s + 2) % 3) * BUF_SZ;

    // 1. issue glds B(s+2), two tiles ahead (oldest vmem this tile)
    if (s + 2 < TILES) {
      const unsigned short* wh = wh_tile + (size_t)(s + 2) * 8192;
      const unsigned short* wl = wl_tile + (size_t)(s + 2) * 8192;
      #pragma unroll
      for (int i = 0; i < 2; ++i) {
        const int c = wid * 2 + i;
        glds16(wh + c * 512 + lane * 8, base_n2 + O_BH + c * 1024);
        glds16(wl + c * 512 + lane * 8, base_n2 + O_BL + c * 1024);
      }
    }
    __builtin_amdgcn_sched_barrier(0);

    // 2. issue A(s+2) loads (clamped)
    {
      int sn = s + 2; if (sn > TILES - 1) sn = TILES - 1;
      pb0 = *(const float4*)(xsrc + (size_t)sn * 32);
      pb1 = *(const float4*)(xsrc + (size_t)sn * 32 + 4);
    }
    __builtin_amdgcn_sched_barrier(0);

    // 3. compute from buf[s%3]
    {
      const char* Ahi = base_c;         const char* Alo = base_c + O_ALO;
      const char* Bh  = base_c + O_BH;  const char* Bl  = base_c + O_BL;
      f16x8 ah[4], al[4], bh[4], bl[4];
      #pragma unroll
      for (int m = 0; m < 4; ++m) {
        ah[m] = *(const f16x8*)(Ahi + aro[m]);
        al[m] = *(const f16x8*)(Alo + aro[m]);
      }
      #pragma unroll
      for (int n = 0; n < 4; ++n) {
        bh[n] = *(const f16x8*)(Bh + bro[n]);
        bl[n] = *(const f16x8*)(Bl + bro[n]);
      }
      __builtin_amdgcn_s_setprio(1);
      #pragma unroll
      for (int m = 0; m < 4; ++m)
        #pragma unroll
        for (int n = 0; n < 4; ++n) {
          acc1[m][n] = __builtin_amdgcn_mfma_f32_16x16x32_f16(ah[m], bh[n], acc1[m][n], 0, 0, 0);
          acc2[m][n] = __builtin_amdgcn_mfma_f32_16x16x32_f16(ah[m], bl[n], acc2[m][n], 0, 0, 0);
          acc2[m][n] = __builtin_amdgcn_mfma_f32_16x16x32_f16(al[m], bh[n], acc2[m][n], 0, 0, 0);
        }
      __builtin_amdgcn_s_setprio(0);
    }

    // 4. convert + ds_write A(s+1) into buf[(s+1)%3]
    if (s + 1 < TILES) {
      float ff[8] = {pa0.x, pa0.y, pa0.z, pa0.w, pa1.x, pa1.y, pa1.z, pa1.w};
      unsigned int hw[4], lw[4];
      #pragma unroll
      for (int q = 0; q < 4; ++q) {
        float f0 = ff[2 * q], f1 = ff[2 * q + 1];
        unsigned short h0 = f2h(f0), h1 = f2h(f1);
        unsigned short l0 = f2h((f0 - h2f(h0)) * 2048.0f);
        unsigned short l1 = f2h((f1 - h2f(h1)) * 2048.0f);
        hw[q] = (unsigned)h0 | ((unsigned)h1 << 16);
        lw[q] = (unsigned)l0 | ((unsigned)l1 << 16);
      }
      *(uint4*)(base_n1 + aw)         = make_uint4(hw[0], hw[1], hw[2], hw[3]);
      *(uint4*)(base_n1 + O_ALO + aw) = make_uint4(lw[0], lw[1], lw[2], lw[3]);
    }
    pa0 = pb0; pa1 = pb1;

    // 5. counted drain + barrier: glds(s+1)/pa(s+1) done (pa wait in step 4
    //    already forced it); glds(s+2) 4 + pa(s+2) 2 stay in flight.
    asm volatile("s_waitcnt vmcnt(6) lgkmcnt(0)" ::: "memory");
    __builtin_amdgcn_sched_barrier(0);
    __builtin_amdgcn_s_barrier();
  }

  // epilogue: logit partial = (acc1 + acc2/2048) / 64
  // C/D layout: col=lane&15, row=(lane>>4)*4+reg
  float* Sp = Spart + (size_t)ks * 8192 * 256;
  #pragma unroll
  for (int m = 0; m < 4; ++m)
    #pragma unroll
    for (int n = 0; n < 4; ++n)
      #pragma unroll
      for (int r = 0; r < 4; ++r) {
        const int t = TM + wm * 64 + m * 16 + (lane >> 4) * 4 + r;
        const int e = wn * 64 + n * 16 + (lane & 15);
        Sp[(size_t)t * 256 + e] =
            (acc1[m][n][r] + acc2[m][n][r] * (1.0f / 2048.0f)) * (1.0f / 64.0f);
      }
}

// ---------------------------------------------------------------------------
// Routing: one wave per token. logit = sum of KS fp32 partials in DOUBLE
// (exact); scores = sigmoid (fp32); then grouped top-k (8 groups, top-2
// group score, top-4 groups, top-8 experts, renorm * 2.5).
// ---------------------------------------------------------------------------
__global__ __launch_bounds__(256) void gate_routing(
    const float* __restrict__ Spart, int KS,
    const float* __restrict__ bias,
    float* __restrict__ outw, float* __restrict__ outi, int T)
{
  const int lane = threadIdx.x & 63;
  const int wave = threadIdx.x >> 6;
  const int t = blockIdx.x * 4 + wave;
  if (t >= T) return;

  double l[4] = {0.0, 0.0, 0.0, 0.0};
  for (int ks = 0; ks < KS; ++ks) {
    float4 p = *(const float4*)(Spart + (size_t)ks * T * 256
                                + (size_t)t * 256 + lane * 4);
    l[0] += (double)p.x; l[1] += (double)p.y;
    l[2] += (double)p.z; l[3] += (double)p.w;
  }

  float4 bi = *(const float4*)(bias + lane * 4);
  float orig[4], s[4];
  #pragma unroll
  for (int u = 0; u < 4; ++u)
    orig[u] = 1.0f / (1.0f + expf(-(float)l[u]));
  s[0] = orig[0] + bi.x; s[1] = orig[1] + bi.y;
  s[2] = orig[2] + bi.z; s[3] = orig[3] + bi.w;

  // per-lane top-2 of its 4 biased scores
  float m1 = -INFINITY, m2 = -INFINITY;
  #pragma unroll
  for (int u = 0; u < 4; ++u) {
    float v = s[u];
    if (v > m1) { m2 = m1; m1 = v; }
    else if (v > m2) { m2 = v; }
  }
  // merge top-2 across the 8 lanes of the group
  #pragma unroll
  for (int off = 1; off < 8; off <<= 1) {
    float o1 = __shfl_xor(m1, off, 64);
    float o2 = __shfl_xor(m2, off, 64);
    if (o1 > m1) { m2 = fmaxf(m1, o2); m1 = o1; }
    else         { m2 = fmaxf(m2, o1); }
  }
  const float gscore = m1 + m2;

  const int g = lane >> 3;
  int rank = 0;
  #pragma unroll
  for (int j = 0; j < 8; ++j) {
    float gs = __shfl(gscore, j * 8, 64);
    rank += (gs > gscore || (gs == gscore && j < g)) ? 1 : 0;
  }
  if (rank >= 4) { s[0] = s[1] = s[2] = s[3] = -INFINITY; }

  float wsum = 0.0f, sel_w = 0.0f;
  int sel_i = 0;
  #pragma unroll
  for (int it = 0; it < 8; ++it) {
    float bv = s[0]; int bu = 0;
    #pragma unroll
    for (int u = 1; u < 4; ++u)
      if (s[u] > bv) { bv = s[u]; bu = u; }
    float v = bv;
    int ix = lane * 4 + bu;
    float og = orig[bu];
    #pragma unroll
    for (int off = 1; off < 64; off <<= 1) {
      float ov  = __shfl_xor(v,  off, 64);
      int   oix = __shfl_xor(ix, off, 64);
      float oog = __shfl_xor(og, off, 64);
      if (ov > v || (ov == v && oix < ix)) { v = ov; ix = oix; og = oog; }
    }
    if (lane == it) { sel_w = og; sel_i = ix; }
    wsum += og;
    if ((ix >> 2) == lane) s[ix & 3] = -INFINITY;
  }

  if (lane < 8) {
    outw[(size_t)t * 8 + lane] = sel_w / wsum * 2.5f;
    outi[(size_t)t * 8 + lane] = (float)sel_i;
  }
}

extern "C" void kernel_launch(void* const* d_in, const int* in_sizes, int n_in,
                              void* d_out, int out_size, void* d_ws, size_t ws_size,
                              hipStream_t stream) {
  const float* x = (const float*)d_in[0];
  const float* w = (const float*)d_in[1];
  const float* b = (const float*)d_in[2];
  const int E = in_sizes[2];                  // 256
  const int D = in_sizes[1] / E;              // 7168
  const int T = in_sizes[0] / D;              // 8192

  unsigned short* Whi = (unsigned short*)d_ws;                       // 3.67 MB
  unsigned short* Wlo = (unsigned short*)((char*)d_ws + (4u << 20)); // 3.67 MB
  float* Spart = (float*)((char*)d_ws + (8u << 20));                 // KS x 8 MB

  // adaptive K-split: largest of {8,4,2} that fits the workspace
  const size_t per_part = (size_t)T * E * 4;
  int KS = 2;
  if (ws_size >= (8u << 20) + 8 * per_part) KS = 8;
  else if (ws_size >= (8u << 20) + 4 * per_part) KS = 4;
  const int TILES = D / (32 * KS);            // 28 for KS=8

  float* outw = (float*)d_out;
  float* outi = outw + (size_t)T * 8;

  convert_w<<<E, 256, 0, stream>>>(w, Whi, Wlo);
  // 1-D grid, ks fastest (XCD-affine for KS=8): KS*(T/128) blocks
  gate_gemm<<<KS * (T / 128), 512, 0, stream>>>(x, Whi, Wlo, Spart, D, TILES, KS);
  gate_routing<<<(T + 3) / 4, 256, 0, stream>>>(Spart, KS, b, outw, outi, T);
}

// Round 18
// 119.458 us; speedup vs baseline: 2.9499x; 1.1261x over previous
//
#include <hip/hip_runtime.h>
#include <hip/hip_bf16.h>
#include <math.h>

// ---------------------------------------------------------------------------
// MoE gate via fp16 hi/lo split MFMA, 3 products (validated round 5):
//   x = xh + xl/2048,  W*64 = wh + wl/2048
//   logit = ( xh·wh + (xh·wl + xl·wh)/2048 ) / 64
// Round 18 = round 17 (134.5us, best) with KS=4 instead of 8:
//   - Spart traffic halves (GEMM write 64->32 MB, routing read 64->32 MB)
//   - grid 256 blocks = exactly 1/CU (no second block-wave, no tail)
//   - ks = bid%4 with bid%8 XCD round-robin => ks==xcd%4 constant per XCD,
//     per-XCD W chunk 1.83 MB < 4 MB L2 (affinity preserved)
//   - accumulation chain 28 -> 56: logit noise ~2.2e-7 (was 1.1e-7),
//     still below the np self-noise scale that r5 passed with margin.
// GEMM body / schedule / layouts / convert_w / routing identical to r17.
// ---------------------------------------------------------------------------

typedef _Float16 f16x8 __attribute__((ext_vector_type(8)));
typedef float    f32x4 __attribute__((ext_vector_type(4)));

__device__ __forceinline__ void glds16(const void* g, void* l) {
  __builtin_amdgcn_global_load_lds(
      (const __attribute__((address_space(1))) void*)g,
      (__attribute__((address_space(3))) void*)l, 16, 0, 0);
}

__device__ __forceinline__ unsigned short f2h(float f) {
  _Float16 h = (_Float16)f;                       // v_cvt_f16_f32, RTN
  return __builtin_bit_cast(unsigned short, h);
}
__device__ __forceinline__ float h2f(unsigned short b) {
  return (float)__builtin_bit_cast(_Float16, b);
}

// swizzle: 64B rows, 4 granules of 16B; bijective in gi per row.
__device__ __forceinline__ int swz(int gi, int row) {
  return gi ^ (row & 3) ^ ((row >> 2) & 3);
}

// ---------------------------------------------------------------------------
// W [256][7168] fp32 -> Whi/Wlo fp16, 256-row pre-swizzled K-tiles (BK=32):
// K-tile t in 0..223 = 256 rows x 32 f16 = 8192 ushorts (16KB).
// element (r,k): gi=k>>3, addr = t*8192 + r*32 + swz(gi,r)*8 + (k&7).
// Whi = fp16(64*W); Wlo = fp16((64*W - Whi) * 2048).   (validated r9/r16)
// ---------------------------------------------------------------------------
__global__ __launch_bounds__(256) void convert_w(
    const float* __restrict__ W,
    unsigned short* __restrict__ Whi, unsigned short* __restrict__ Wlo)
{
  const int e = blockIdx.x;           // expert/row 0..255
  const int t = threadIdx.x;          // 0..255, use 224 (one K-tile each)
  if (t >= 224) return;
  const float* src = W + (size_t)e * 7168 + t * 32;
  const size_t tbase = (size_t)t * 8192 + (size_t)e * 32;
  #pragma unroll
  for (int g = 0; g < 4; ++g) {       // granule gi = g, k = g*8..g*8+7
    unsigned int hw[4], lw[4];
    #pragma unroll
    for (int p = 0; p < 4; ++p) {
      float f0 = src[g * 8 + 2 * p] * 64.0f;
      float f1 = src[g * 8 + 2 * p + 1] * 64.0f;
      unsigned short h0 = f2h(f0), h1 = f2h(f1);
      unsigned short l0 = f2h((f0 - h2f(h0)) * 2048.0f);
      unsigned short l1 = f2h((f1 - h2f(h1)) * 2048.0f);
      hw[p] = (unsigned)h0 | ((unsigned)h1 << 16);
      lw[p] = (unsigned)l0 | ((unsigned)l1 << 16);
    }
    const size_t base = tbase + (size_t)(swz(g, e) * 8);
    *(uint4*)(Whi + base) = make_uint4(hw[0], hw[1], hw[2], hw[3]);
    *(uint4*)(Wlo + base) = make_uint4(lw[0], lw[1], lw[2], lw[3]);
  }
}

// ---------------------------------------------------------------------------
// GEMM: BM=128, BN=256, BK=32, K-split KS. 512 threads = 8 waves (2Mx4N),
// wave tile 64x64 = 4x4 frags of 16x16x32 f16 MFMA, 3 products.
// TRIPLE-buffered LDS (3 x 48KB = 144KB). Per tile s:
//   1. issue glds B(s+2) -> buf[(s+2)%3]   (4 glds/wave, 2 tiles ahead)
//   2. issue A(s+2) loads (2/thread, clamped)
//   3. compute buf[s%3] (setprio)
//   4. convert pa(s+1) -> ds_write A -> buf[(s+1)%3]
//   5. vmcnt(6) + lgkmcnt(0) + s_barrier   (glds(s+2)+pa(s+2) in flight)
// Grid 1-D: ks = bid % KS (XCD-affine), bm = bid / KS.
// ---------------------------------------------------------------------------
#define BUF_SZ   49152
#define O_ALO    8192
#define O_BH     16384
#define O_BL     32768

__global__ __launch_bounds__(512, 2) void gate_gemm(
    const float* __restrict__ X,
    const unsigned short* __restrict__ Whi,
    const unsigned short* __restrict__ Wlo,
    float* __restrict__ Spart, int D, int TILES, int KS)
{
  __shared__ char lds[147456];   // 3 buffers

  const int bid = blockIdx.x;
  const int ks = bid % KS;                 // XCD-affine
  const int bm = bid / KS;
  const int tid = threadIdx.x, lane = tid & 63, wid = tid >> 6;
  const int wm = wid >> 2, wn = wid & 3;   // 2M x 4N wave grid
  const int TM = bm * 128;
  const int k0base = ks * TILES * 32;      // K-chunk start

  // A staging: 4 threads per row, 8 contiguous fp32 each (one granule)
  const int srow = tid >> 2, sg = tid & 3;
  const float* xsrc = X + (size_t)(TM + srow) * D + k0base + sg * 8;
  const int aw = srow * 64 + swz(sg, srow) * 16;   // byte offset

  const unsigned short* wh_tile = Whi + (size_t)(ks * TILES) * 8192;
  const unsigned short* wl_tile = Wlo + (size_t)(ks * TILES) * 8192;

  f32x4 acc1[4][4], acc2[4][4];
  #pragma unroll
  for (int m = 0; m < 4; ++m)
    #pragma unroll
    for (int n = 0; n < 4; ++n) { acc1[m][n] = (f32x4)0.0f; acc2[m][n] = (f32x4)0.0f; }

  // fragment read byte offsets, fixed per lane
  int aro[4], bro[4];
  const int gi = lane >> 4;
  #pragma unroll
  for (int m = 0; m < 4; ++m) {
    const int row = wm * 64 + m * 16 + (lane & 15);
    aro[m] = row * 64 + swz(gi, row) * 16;
  }
  #pragma unroll
  for (int n = 0; n < 4; ++n) {
    const int row = wn * 64 + n * 16 + (lane & 15);
    bro[n] = row * 64 + swz(gi, row) * 16;
  }

  // ---- prologue: A(0) loads first, stage B(0)->buf0, B(1)->buf1,
  //      A(0) convert+write, prefetch pa(1) ----
  float4 pa0, pa1, pb0, pb1;
  {
    float4 a0 = *(const float4*)(xsrc);          // oldest in queue
    float4 a1 = *(const float4*)(xsrc + 4);
    #pragma unroll
    for (int i = 0; i < 2; ++i) {                // glds B(0) (4/wave)
      const int c = wid * 2 + i;                 // chunk 0..15, wave-uniform
      glds16(wh_tile + c * 512 + lane * 8, lds + O_BH + c * 1024);
      glds16(wl_tile + c * 512 + lane * 8, lds + O_BL + c * 1024);
    }
    if (TILES > 1) {                             // glds B(1) (4/wave)
      #pragma unroll
      for (int i = 0; i < 2; ++i) {
        const int c = wid * 2 + i;
        glds16(wh_tile + 8192 + c * 512 + lane * 8, lds + BUF_SZ + O_BH + c * 1024);
        glds16(wl_tile + 8192 + c * 512 + lane * 8, lds + BUF_SZ + O_BL + c * 1024);
      }
    }
    __builtin_amdgcn_sched_barrier(0);
    // prefetch pa(1) (newest)
    const int s1 = (TILES > 1) ? 1 : 0;
    pa0 = *(const float4*)(xsrc + (size_t)s1 * 32);
    pa1 = *(const float4*)(xsrc + (size_t)s1 * 32 + 4);
    __builtin_amdgcn_sched_barrier(0);
    // convert + write A(0) into buf0 (compiler waits a0/a1 here)
    float ff[8] = {a0.x, a0.y, a0.z, a0.w, a1.x, a1.y, a1.z, a1.w};
    unsigned int hw[4], lw[4];
    #pragma unroll
    for (int q = 0; q < 4; ++q) {
      float f0 = ff[2 * q], f1 = ff[2 * q + 1];
      unsigned short h0 = f2h(f0), h1 = f2h(f1);
      unsigned short l0 = f2h((f0 - h2f(h0)) * 2048.0f);
      unsigned short l1 = f2h((f1 - h2f(h1)) * 2048.0f);
      hw[q] = (unsigned)h0 | ((unsigned)h1 << 16);
      lw[q] = (unsigned)l0 | ((unsigned)l1 << 16);
    }
    *(uint4*)(lds + aw)         = make_uint4(hw[0], hw[1], hw[2], hw[3]);
    *(uint4*)(lds + O_ALO + aw) = make_uint4(lw[0], lw[1], lw[2], lw[3]);
    __builtin_amdgcn_sched_barrier(0);
  }
  // B(0) done: after-glds(0) items = glds(1) 4 + pa(1) 2 = 6
  asm volatile("s_waitcnt vmcnt(6) lgkmcnt(0)" ::: "memory");
  __builtin_amdgcn_sched_barrier(0);
  __builtin_amdgcn_s_barrier();

  for (int s = 0; s < TILES; ++s) {
    char* base_c  = lds + (s % 3) * BUF_SZ;
    char* base_n1 = lds + ((s + 1) % 3) * BUF_SZ;
    char* base_n2 = lds + ((s + 2) % 3) * BUF_SZ;

    // 1. issue glds B(s+2), two tiles ahead (oldest vmem this tile)
    if (s + 2 < TILES) {
      const unsigned short* wh = wh_tile + (size_t)(s + 2) * 8192;
      const unsigned short* wl = wl_tile + (size_t)(s + 2) * 8192;
      #pragma unroll
      for (int i = 0; i < 2; ++i) {
        const int c = wid * 2 + i;
        glds16(wh + c * 512 + lane * 8, base_n2 + O_BH + c * 1024);
        glds16(wl + c * 512 + lane * 8, base_n2 + O_BL + c * 1024);
      }
    }
    __builtin_amdgcn_sched_barrier(0);

    // 2. issue A(s+2) loads (clamped)
    {
      int sn = s + 2; if (sn > TILES - 1) sn = TILES - 1;
      pb0 = *(const float4*)(xsrc + (size_t)sn * 32);
      pb1 = *(const float4*)(xsrc + (size_t)sn * 32 + 4);
    }
    __builtin_amdgcn_sched_barrier(0);

    // 3. compute from buf[s%3]
    {
      const char* Ahi = base_c;         const char* Alo = base_c + O_ALO;
      const char* Bh  = base_c + O_BH;  const char* Bl  = base_c + O_BL;
      f16x8 ah[4], al[4], bh[4], bl[4];
      #pragma unroll
      for (int m = 0; m < 4; ++m) {
        ah[m] = *(const f16x8*)(Ahi + aro[m]);
        al[m] = *(const f16x8*)(Alo + aro[m]);
      }
      #pragma unroll
      for (int n = 0; n < 4; ++n) {
        bh[n] = *(const f16x8*)(Bh + bro[n]);
        bl[n] = *(const f16x8*)(Bl + bro[n]);
      }
      __builtin_amdgcn_s_setprio(1);
      #pragma unroll
      for (int m = 0; m < 4; ++m)
        #pragma unroll
        for (int n = 0; n < 4; ++n) {
          acc1[m][n] = __builtin_amdgcn_mfma_f32_16x16x32_f16(ah[m], bh[n], acc1[m][n], 0, 0, 0);
          acc2[m][n] = __builtin_amdgcn_mfma_f32_16x16x32_f16(ah[m], bl[n], acc2[m][n], 0, 0, 0);
          acc2[m][n] = __builtin_amdgcn_mfma_f32_16x16x32_f16(al[m], bh[n], acc2[m][n], 0, 0, 0);
        }
      __builtin_amdgcn_s_setprio(0);
    }

    // 4. convert + ds_write A(s+1) into buf[(s+1)%3]
    if (s + 1 < TILES) {
      float ff[8] = {pa0.x, pa0.y, pa0.z, pa0.w, pa1.x, pa1.y, pa1.z, pa1.w};
      unsigned int hw[4], lw[4];
      #pragma unroll
      for (int q = 0; q < 4; ++q) {
        float f0 = ff[2 * q], f1 = ff[2 * q + 1];
        unsigned short h0 = f2h(f0), h1 = f2h(f1);
        unsigned short l0 = f2h((f0 - h2f(h0)) * 2048.0f);
        unsigned short l1 = f2h((f1 - h2f(h1)) * 2048.0f);
        hw[q] = (unsigned)h0 | ((unsigned)h1 << 16);
        lw[q] = (unsigned)l0 | ((unsigned)l1 << 16);
      }
      *(uint4*)(base_n1 + aw)         = make_uint4(hw[0], hw[1], hw[2], hw[3]);
      *(uint4*)(base_n1 + O_ALO + aw) = make_uint4(lw[0], lw[1], lw[2], lw[3]);
    }
    pa0 = pb0; pa1 = pb1;

    // 5. counted drain + barrier: glds(s+1)/pa(s+1) done (pa wait in step 4
    //    already forced it); glds(s+2) 4 + pa(s+2) 2 stay in flight.
    asm volatile("s_waitcnt vmcnt(6) lgkmcnt(0)" ::: "memory");
    __builtin_amdgcn_sched_barrier(0);
    __builtin_amdgcn_s_barrier();
  }

  // epilogue: logit partial = (acc1 + acc2/2048) / 64
  // C/D layout: col=lane&15, row=(lane>>4)*4+reg
  float* Sp = Spart + (size_t)ks * 8192 * 256;
  #pragma unroll
  for (int m = 0; m < 4; ++m)
    #pragma unroll
    for (int n = 0; n < 4; ++n)
      #pragma unroll
      for (int r = 0; r < 4; ++r) {
        const int t = TM + wm * 64 + m * 16 + (lane >> 4) * 4 + r;
        const int e = wn * 64 + n * 16 + (lane & 15);
        Sp[(size_t)t * 256 + e] =
            (acc1[m][n][r] + acc2[m][n][r] * (1.0f / 2048.0f)) * (1.0f / 64.0f);
      }
}

// ---------------------------------------------------------------------------
// Routing: one wave per token. logit = sum of KS fp32 partials in DOUBLE
// (exact); scores = sigmoid (fp32); then grouped top-k (8 groups, top-2
// group score, top-4 groups, top-8 experts, renorm * 2.5).
// ---------------------------------------------------------------------------
__global__ __launch_bounds__(256) void gate_routing(
    const float* __restrict__ Spart, int KS,
    const float* __restrict__ bias,
    float* __restrict__ outw, float* __restrict__ outi, int T)
{
  const int lane = threadIdx.x & 63;
  const int wave = threadIdx.x >> 6;
  const int t = blockIdx.x * 4 + wave;
  if (t >= T) return;

  double l[4] = {0.0, 0.0, 0.0, 0.0};
  for (int ks = 0; ks < KS; ++ks) {
    float4 p = *(const float4*)(Spart + (size_t)ks * T * 256
                                + (size_t)t * 256 + lane * 4);
    l[0] += (double)p.x; l[1] += (double)p.y;
    l[2] += (double)p.z; l[3] += (double)p.w;
  }

  float4 bi = *(const float4*)(bias + lane * 4);
  float orig[4], s[4];
  #pragma unroll
  for (int u = 0; u < 4; ++u)
    orig[u] = 1.0f / (1.0f + expf(-(float)l[u]));
  s[0] = orig[0] + bi.x; s[1] = orig[1] + bi.y;
  s[2] = orig[2] + bi.z; s[3] = orig[3] + bi.w;

  // per-lane top-2 of its 4 biased scores
  float m1 = -INFINITY, m2 = -INFINITY;
  #pragma unroll
  for (int u = 0; u < 4; ++u) {
    float v = s[u];
    if (v > m1) { m2 = m1; m1 = v; }
    else if (v > m2) { m2 = v; }
  }
  // merge top-2 across the 8 lanes of the group
  #pragma unroll
  for (int off = 1; off < 8; off <<= 1) {
    float o1 = __shfl_xor(m1, off, 64);
    float o2 = __shfl_xor(m2, off, 64);
    if (o1 > m1) { m2 = fmaxf(m1, o2); m1 = o1; }
    else         { m2 = fmaxf(m2, o1); }
  }
  const float gscore = m1 + m2;

  const int g = lane >> 3;
  int rank = 0;
  #pragma unroll
  for (int j = 0; j < 8; ++j) {
    float gs = __shfl(gscore, j * 8, 64);
    rank += (gs > gscore || (gs == gscore && j < g)) ? 1 : 0;
  }
  if (rank >= 4) { s[0] = s[1] = s[2] = s[3] = -INFINITY; }

  float wsum = 0.0f, sel_w = 0.0f;
  int sel_i = 0;
  #pragma unroll
  for (int it = 0; it < 8; ++it) {
    float bv = s[0]; int bu = 0;
    #pragma unroll
    for (int u = 1; u < 4; ++u)
      if (s[u] > bv) { bv = s[u]; bu = u; }
    float v = bv;
    int ix = lane * 4 + bu;
    float og = orig[bu];
    #pragma unroll
    for (int off = 1; off < 64; off <<= 1) {
      float ov  = __shfl_xor(v,  off, 64);
      int   oix = __shfl_xor(ix, off, 64);
      float oog = __shfl_xor(og, off, 64);
      if (ov > v || (ov == v && oix < ix)) { v = ov; ix = oix; og = oog; }
    }
    if (lane == it) { sel_w = og; sel_i = ix; }
    wsum += og;
    if ((ix >> 2) == lane) s[ix & 3] = -INFINITY;
  }

  if (lane < 8) {
    outw[(size_t)t * 8 + lane] = sel_w / wsum * 2.5f;
    outi[(size_t)t * 8 + lane] = (float)sel_i;
  }
}

extern "C" void kernel_launch(void* const* d_in, const int* in_sizes, int n_in,
                              void* d_out, int out_size, void* d_ws, size_t ws_size,
                              hipStream_t stream) {
  const float* x = (const float*)d_in[0];
  const float* w = (const float*)d_in[1];
  const float* b = (const float*)d_in[2];
  const int E = in_sizes[2];                  // 256
  const int D = in_sizes[1] / E;              // 7168
  const int T = in_sizes[0] / D;              // 8192

  unsigned short* Whi = (unsigned short*)d_ws;                       // 3.67 MB
  unsigned short* Wlo = (unsigned short*)((char*)d_ws + (4u << 20)); // 3.67 MB
  float* Spart = (float*)((char*)d_ws + (8u << 20));                 // KS x 8 MB

  // K-split 4 (halved Spart traffic vs 8; chain 56 within noise budget)
  const size_t per_part = (size_t)T * E * 4;
  int KS = 2;
  if (ws_size >= (8u << 20) + 4 * per_part) KS = 4;
  const int TILES = D / (32 * KS);            // 56 for KS=4

  float* outw = (float*)d_out;
  float* outi = outw + (size_t)T * 8;

  convert_w<<<E, 256, 0, stream>>>(w, Whi, Wlo);
  // 1-D grid, ks fastest (XCD-affine): KS*(T/128) = 256 blocks at KS=4
  gate_gemm<<<KS * (T / 128), 512, 0, stream>>>(x, Whi, Wlo, Spart, D, TILES, KS);
  gate_routing<<<(T + 3) / 4, 256, 0, stream>>>(Spart, KS, b, outw, outi, T);
}